// Round 5
// baseline (413.173 us; speedup 1.0000x reference)
//
#include <hip/hip_runtime.h>
#include <cstdint>
#include <cstddef>

// AttnBlock: B=4, C=512, H=W=64 (N=4096). All-fp32 I/O, bf16 MFMA internally.
// R5: gemm_nt K-loop -> 3-buffer depth-2 pipeline with counted vmcnt(4) +
//     raw s_barrier (T3/T4). Rest identical to R4 (fixed-offset softmax).

#define CDIM 512
#define NSP  4096
#define NB   4
#define M0   12.0f

using bf16x8 = __attribute__((ext_vector_type(8))) __bf16;
using f32x4  = __attribute__((ext_vector_type(4))) float;
using u16x4  = __attribute__((ext_vector_type(4))) unsigned short;
using h8     = __attribute__((ext_vector_type(8))) _Float16;

__device__ __forceinline__ unsigned short f2bf(float f) {
  unsigned int u = __float_as_uint(f);
  u += 0x7fffu + ((u >> 16) & 1u);
  return (unsigned short)(u >> 16);
}

__device__ __forceinline__ void async_copy16(const unsigned short* g, unsigned short* l) {
  __builtin_amdgcn_global_load_lds(
      (const __attribute__((address_space(1))) void*)g,
      (__attribute__((address_space(3))) void*)l, 16, 0, 0);
}

// ---------------- GroupNorm stats: one block per (b, group) ----------------
__global__ __launch_bounds__(256) void gn_stats(const float* __restrict__ x,
                                                float* __restrict__ stats) {
  const size_t base = (size_t)blockIdx.x * 65536;  // 16 ch * 4096, contiguous
  const float4* p = (const float4*)(x + base);
  float s = 0.f, ss = 0.f;
  for (int i = threadIdx.x; i < 16384; i += 256) {
    float4 v = p[i];
    s  += v.x + v.y + v.z + v.w;
    ss += v.x*v.x + v.y*v.y + v.z*v.z + v.w*v.w;
  }
  for (int off = 32; off; off >>= 1) {
    s  += __shfl_xor(s, off);
    ss += __shfl_xor(ss, off);
  }
  __shared__ float rs[4], rss[4];
  const int w = threadIdx.x >> 6;
  if ((threadIdx.x & 63) == 0) { rs[w] = s; rss[w] = ss; }
  __syncthreads();
  if (threadIdx.x == 0) {
    float S  = rs[0] + rs[1] + rs[2] + rs[3];
    float SS = rss[0] + rss[1] + rss[2] + rss[3];
    float mean = S * (1.f / 65536.f);
    float var  = SS * (1.f / 65536.f) - mean * mean;
    stats[2 * blockIdx.x]     = mean;
    stats[2 * blockIdx.x + 1] = rsqrtf(var + 1e-6f);
  }
}

// ------------- normalize + transpose: x(B,C,N) f32 -> Hnt(B,N,C) bf16 -------
__global__ __launch_bounds__(256) void norm_transpose(
    const float* __restrict__ x, const float* __restrict__ stats,
    const float* __restrict__ gns, const float* __restrict__ gnb,
    unsigned short* __restrict__ hnt) {
  __shared__ float tile[64][65];
  const int b  = blockIdx.z;
  const int c0 = blockIdx.y * 64, n0 = blockIdx.x * 64;
  const int tx = threadIdx.x & 63, ty = threadIdx.x >> 6;
  for (int i = 0; i < 16; ++i) {
    int cl = ty * 16 + i;
    int c  = c0 + cl;
    int g  = c >> 4;
    float mean = stats[(b * 32 + g) * 2];
    float rstd = stats[(b * 32 + g) * 2 + 1];
    float v = x[((size_t)(b * CDIM + c)) * NSP + n0 + tx];
    tile[cl][tx] = (v - mean) * rstd * gns[c] + gnb[c];
  }
  __syncthreads();
  for (int i = 0; i < 16; ++i) {
    int nl = ty * 16 + i;
    hnt[((size_t)(b * NSP + n0 + nl)) * CDIM + c0 + tx] = f2bf(tile[tx][nl]);
  }
}

// ---------------- fp32 -> bf16 weight conversion (4 weights, one launch) ----
__global__ __launch_bounds__(256) void weights_to_bf16(
    const float* __restrict__ w0, const float* __restrict__ w1,
    const float* __restrict__ w2, const float* __restrict__ w3,
    unsigned short* __restrict__ o0, unsigned short* __restrict__ o1,
    unsigned short* __restrict__ o2, unsigned short* __restrict__ o3) {
  const float* s; unsigned short* o;
  switch (blockIdx.y) {
    case 0: s = w0; o = o0; break;
    case 1: s = w1; o = o1; break;
    case 2: s = w2; o = o2; break;
    default: s = w3; o = o3; break;
  }
  int i = blockIdx.x * 256 + threadIdx.x;
  float4 v = ((const float4*)s)[i];
  u16x4 r = {f2bf(v.x), f2bf(v.y), f2bf(v.z), f2bf(v.w)};
  *(u16x4*)(o + (size_t)i * 4) = r;
}

// ---------------- NT GEMM: D[M,N] = A[M,K] @ Bt[N,K]^T ----------------
// BIAS_MODE: 0 none, 1 per-row bias[m], 2 per-col bias[n]
// OUT_MODE:  0 f32, 1 bf16, 2 fp16
// SPLITK:    blockIdx.z = split*NB + b; k-range [split*kLen,+kLen); D off z*M*N
// EXPL:      store exp(fma(acc,scale,-M0)); accumulate row sums into lsum[b*M+row]
// K-loop: 3-buffer LDS pipeline, depth-2 prefetch, counted vmcnt (T3/T4).
template <int BIAS_MODE, int OUT_MODE, int RESID, int SPLITK, int EXPL>
__global__ __launch_bounds__(256) void gemm_nt(
    const unsigned short* __restrict__ A, const unsigned short* __restrict__ Bt,
    void* __restrict__ Dv, const float* __restrict__ bias,
    const float* __restrict__ resid, float* __restrict__ lsum,
    int M, int N, int K, float scale,
    long sA, long sB, long sD, long sR, int kLen) {
  __shared__ unsigned short lsA[3][128 * 32];
  __shared__ unsigned short lsB[3][128 * 32];
  const int tid = threadIdx.x;
  const int w = tid >> 6, lane = tid & 63;
  const int wr = w >> 1, wc = w & 1;
  const int b = SPLITK ? (blockIdx.z & 3) : blockIdx.z;
  const int bm0 = blockIdx.y * 128, bn0 = blockIdx.x * 128;
  const unsigned short* Ab = A + (size_t)b * sA;
  const unsigned short* Bb = Bt + (size_t)b * sB;
  const size_t dOff = SPLITK ? (size_t)blockIdx.z * (size_t)M * N
                             : (size_t)b * (size_t)sD;
  const int kStart = SPLITK ? (blockIdx.z >> 2) * kLen : 0;
  const int niters = (SPLITK ? kLen : K) / 32;

  f32x4 acc[4][4] = {};
  const int r0  = w * 16 + (lane >> 2);
  const int kof = (lane & 3) * 8;
  const int fr  = lane & 15, kf = (lane >> 4) * 8;

  // stage K-step t into buffer buf (4 x 16B async loads per thread)
  auto stage = [&](int t, int buf) {
    const int k0 = kStart + t * 32;
#pragma unroll
    for (int it = 0; it < 2; ++it) {
      int row = it * 64 + r0;
      async_copy16(Ab + (size_t)(bm0 + row) * K + k0 + kof, &lsA[buf][row * 32 + kof]);
      async_copy16(Bb + (size_t)(bn0 + row) * K + k0 + kof, &lsB[buf][row * 32 + kof]);
    }
  };

  auto compute = [&](int cur) {
    bf16x8 af[4], bff[4];
#pragma unroll
    for (int i = 0; i < 4; ++i) {
      af[i]  = *(const bf16x8*)(&lsA[cur][(wr * 64 + i * 16 + fr) * 32 + kf]);
      bff[i] = *(const bf16x8*)(&lsB[cur][(wc * 64 + i * 16 + fr) * 32 + kf]);
    }
#pragma unroll
    for (int i = 0; i < 4; ++i)
#pragma unroll
      for (int j = 0; j < 4; ++j)
        acc[i][j] = __builtin_amdgcn_mfma_f32_16x16x32_bf16(af[i], bff[j], acc[i][j], 0, 0, 0);
  };

  // prologue: two tiles in flight
  stage(0, 0);
  stage(1, 1);

  // main loop: wait for cur (4 newest loads may stay in flight), barrier,
  // issue t+2, read+MFMA cur. Single barrier per iter: it orders iter t-1's
  // ds_reads (complete before each wave's own MFMAs issue) against iter t's
  // overwrite of that buffer.
  for (int t = 0; t < niters - 1; ++t) {
    asm volatile("s_waitcnt vmcnt(4)\ns_barrier" ::: "memory");
    if (t + 2 < niters) stage(t + 2, (t + 2) % 3);
    compute(t % 3);
  }
  // tail: only cur's loads remain outstanding
  asm volatile("s_waitcnt vmcnt(0)\ns_barrier" ::: "memory");
  compute((niters - 1) % 3);

  const int col_l = lane & 15, row_l = (lane >> 4) * 4;
  float rs[4][4];
  if (EXPL)
    for (int i = 0; i < 4; ++i)
      for (int r = 0; r < 4; ++r) rs[i][r] = 0.f;

  for (int i = 0; i < 4; ++i)
    for (int j = 0; j < 4; ++j) {
      int gr = bm0 + wr * 64 + i * 16 + row_l;
      int gc = bn0 + wc * 64 + j * 16 + col_l;
      for (int r = 0; r < 4; ++r) {
        float v;
        if (EXPL) {
          v = __expf(fmaf(acc[i][j][r], scale, -M0));
          rs[i][r] += v;
        } else {
          v = acc[i][j][r] * scale;
          if (BIAS_MODE == 1) v += bias[gr + r];
          if (BIAS_MODE == 2) v += bias[gc];
          if (RESID) v += resid[(size_t)b * sR + (size_t)(gr + r) * N + gc];
        }
        if (OUT_MODE == 1)
          ((unsigned short*)Dv)[dOff + (size_t)(gr + r) * N + gc] = f2bf(v);
        else if (OUT_MODE == 2)
          ((_Float16*)Dv)[dOff + (size_t)(gr + r) * N + gc] = (_Float16)v;
        else
          ((float*)Dv)[dOff + (size_t)(gr + r) * N + gc] = v;
      }
    }

  if (EXPL) {
    // reduce each (i,r) row partial across the 16 col lanes, then atomicAdd
#pragma unroll
    for (int i = 0; i < 4; ++i)
#pragma unroll
      for (int r = 0; r < 4; ++r) {
        float v = rs[i][r];
        v += __shfl_xor(v, 1); v += __shfl_xor(v, 2);
        v += __shfl_xor(v, 4); v += __shfl_xor(v, 8);
        if (col_l == 0) {
          int gr = bm0 + wr * 64 + i * 16 + row_l + r;
          atomicAdd(&lsum[(size_t)b * M + gr], v);
        }
      }
  }
}

// ---------------- reduce: ot = (Op0 + Op1) / l  -> bf16 ----------------
__global__ __launch_bounds__(256) void reduce_div(const _Float16* __restrict__ Op,
                                                  const float* __restrict__ l,
                                                  unsigned short* __restrict__ ot) {
  const size_t stride = (size_t)NB * NSP * CDIM;  // elems per split
  size_t base = ((size_t)blockIdx.x * 256 + threadIdx.x) * 8;
  float linv = 1.f / l[base >> 9];  // row = base / 512
  h8 a = *(const h8*)(Op + base);
  h8 c = *(const h8*)(Op + stride + base);
  u16x4 o0, o1;
#pragma unroll
  for (int i = 0; i < 4; ++i) {
    o0[i] = f2bf(((float)a[i] + (float)c[i]) * linv);
    o1[i] = f2bf(((float)a[i + 4] + (float)c[i + 4]) * linv);
  }
  *(u16x4*)(ot + base) = o0;
  *(u16x4*)(ot + base + 4) = o1;
}

extern "C" void kernel_launch(void* const* d_in, const int* in_sizes, int n_in,
                              void* d_out, int out_size, void* d_ws, size_t ws_size,
                              hipStream_t stream) {
  const float* hs  = (const float*)d_in[0];
  const float* gns = (const float*)d_in[1];
  const float* gnb = (const float*)d_in[2];
  const float* wq  = (const float*)d_in[3];
  const float* bq  = (const float*)d_in[4];
  const float* wk  = (const float*)d_in[5];
  const float* bk  = (const float*)d_in[6];
  const float* wv  = (const float*)d_in[7];
  const float* bv  = (const float*)d_in[8];
  const float* wp  = (const float*)d_in[9];
  const float* bp  = (const float*)d_in[10];

  char* p = (char*)d_ws;
  unsigned short* wqb = (unsigned short*)p; p += (size_t)CDIM * CDIM * 2;
  unsigned short* wkb = (unsigned short*)p; p += (size_t)CDIM * CDIM * 2;
  unsigned short* wvb = (unsigned short*)p; p += (size_t)CDIM * CDIM * 2;
  unsigned short* wpb = (unsigned short*)p; p += (size_t)CDIM * CDIM * 2;
  const size_t bn = (size_t)NSP * CDIM;  // 2M elements per batch
  unsigned short* hnt = (unsigned short*)p; p += NB * bn * 2;   // also reused as ot
  unsigned short* qt  = (unsigned short*)p; p += NB * bn * 2;
  unsigned short* kt  = (unsigned short*)p; p += NB * bn * 2;
  unsigned short* vcn = (unsigned short*)p; p += NB * bn * 2;
  unsigned short* P   = (unsigned short*)p; p += (size_t)NB * NSP * NSP * 2;  // 128 MiB
  _Float16* Op = (_Float16*)p;  p += (size_t)2 * NB * bn * 2;   // 32 MiB (2 splits)
  float* lsum  = (float*)p;     p += (size_t)NB * NSP * 4;      // 64 KiB
  float* stats = (float*)p;     p += 256 * 4;
  unsigned short* ot = hnt;  // hnt dead after the QKV projections

  hipMemsetAsync(lsum, 0, (size_t)NB * NSP * 4, stream);
  weights_to_bf16<<<dim3(256, 4), 256, 0, stream>>>(wq, wk, wv, wp, wqb, wkb, wvb, wpb);
  gn_stats<<<128, 256, 0, stream>>>(hs, stats);
  norm_transpose<<<dim3(64, 8, 4), 256, 0, stream>>>(hs, stats, gns, gnb, hnt);

  const long sBN = (long)bn;
  const long sPP = (long)NSP * NSP;
  // Qt[b] (4096x512) = Hnt[b] @ Wq^T + bq (per-col)
  gemm_nt<2, 1, 0, 0, 0><<<dim3(4, 32, NB), 256, 0, stream>>>(
      hnt, wqb, qt, bq, nullptr, nullptr, NSP, CDIM, CDIM, 1.f, sBN, 0, sBN, 0, 0);
  gemm_nt<2, 1, 0, 0, 0><<<dim3(4, 32, NB), 256, 0, stream>>>(
      hnt, wkb, kt, bk, nullptr, nullptr, NSP, CDIM, CDIM, 1.f, sBN, 0, sBN, 0, 0);
  // Vcn[b] (512x4096) = Wv @ Hnt[b]^T + bv (per-row)
  gemm_nt<1, 1, 0, 0, 0><<<dim3(32, 4, NB), 256, 0, stream>>>(
      wvb, hnt, vcn, bv, nullptr, nullptr, CDIM, NSP, CDIM, 1.f, 0, sBN, sBN, 0, 0);

  // P[b] (4096x4096 bf16) = exp(Qt Kt^T * C^-0.5 - M0); lsum[b][i] += row sums
  const float sc = 0.044194173824159216f;  // 512^-0.5
  gemm_nt<0, 1, 0, 0, 1><<<dim3(32, 32, NB), 256, 0, stream>>>(
      qt, kt, P, nullptr, nullptr, lsum, NSP, NSP, CDIM, sc, sBN, sBN, sPP, 0, 0);

  // PV split-K=2: Op[z] (4096x512 fp16) = P[b][:, ks:ks+2048] @ Vcn[b][:, same]^T
  gemm_nt<0, 2, 0, 1, 0><<<dim3(4, 32, 2 * NB), 256, 0, stream>>>(
      P, vcn, Op, nullptr, nullptr, nullptr, NSP, CDIM, NSP, 1.f,
      sPP, sBN, 0, 0, NSP / 2);

  // ot (bf16) = (Op0 + Op1) / lsum
  reduce_div<<<4096, 256, 0, stream>>>(Op, lsum, ot);

  // out[b] (512x4096 fp32) = Wp @ Ot[b]^T + bp (per-row) + residual
  gemm_nt<1, 0, 1, 0, 0><<<dim3(32, 4, NB), 256, 0, stream>>>(
      wpb, ot, (float*)d_out, bp, hs, nullptr, CDIM, NSP, CDIM, 1.f, 0, sBN, sBN, sBN, 0);
}

// Round 6
// 375.708 us; speedup vs baseline: 1.0997x; 1.0997x over previous
//
#include <hip/hip_runtime.h>
#include <cstdint>
#include <cstddef>

// AttnBlock: B=4, C=512, H=W=64 (N=4096). All-fp32 I/O, bf16 MFMA internally.
// R6: QK^T and PV moved to a 256x256/BK=64 8-wave phase-split kernel
//     (T2 swizzle + T3 phases + T4 single-drain + T5 setprio).
//     Projections keep the proven R4 128x128 2-buffer kernel.

#define CDIM 512
#define NSP  4096
#define NB   4
#define M0   12.0f

using bf16x8 = __attribute__((ext_vector_type(8))) __bf16;
using f32x4  = __attribute__((ext_vector_type(4))) float;
using u16x4  = __attribute__((ext_vector_type(4))) unsigned short;
using h8     = __attribute__((ext_vector_type(8))) _Float16;

__device__ __forceinline__ unsigned short f2bf(float f) {
  unsigned int u = __float_as_uint(f);
  u += 0x7fffu + ((u >> 16) & 1u);
  return (unsigned short)(u >> 16);
}

__device__ __forceinline__ void async_copy16(const unsigned short* g, unsigned short* l) {
  __builtin_amdgcn_global_load_lds(
      (const __attribute__((address_space(1))) void*)g,
      (__attribute__((address_space(3))) void*)l, 16, 0, 0);
}

// ---------------- GroupNorm stats: one block per (b, group) ----------------
__global__ __launch_bounds__(256) void gn_stats(const float* __restrict__ x,
                                                float* __restrict__ stats) {
  const size_t base = (size_t)blockIdx.x * 65536;  // 16 ch * 4096, contiguous
  const float4* p = (const float4*)(x + base);
  float s = 0.f, ss = 0.f;
  for (int i = threadIdx.x; i < 16384; i += 256) {
    float4 v = p[i];
    s  += v.x + v.y + v.z + v.w;
    ss += v.x*v.x + v.y*v.y + v.z*v.z + v.w*v.w;
  }
  for (int off = 32; off; off >>= 1) {
    s  += __shfl_xor(s, off);
    ss += __shfl_xor(ss, off);
  }
  __shared__ float rs[4], rss[4];
  const int w = threadIdx.x >> 6;
  if ((threadIdx.x & 63) == 0) { rs[w] = s; rss[w] = ss; }
  __syncthreads();
  if (threadIdx.x == 0) {
    float S  = rs[0] + rs[1] + rs[2] + rs[3];
    float SS = rss[0] + rss[1] + rss[2] + rss[3];
    float mean = S * (1.f / 65536.f);
    float var  = SS * (1.f / 65536.f) - mean * mean;
    stats[2 * blockIdx.x]     = mean;
    stats[2 * blockIdx.x + 1] = rsqrtf(var + 1e-6f);
  }
}

// ------------- normalize + transpose: x(B,C,N) f32 -> Hnt(B,N,C) bf16 -------
__global__ __launch_bounds__(256) void norm_transpose(
    const float* __restrict__ x, const float* __restrict__ stats,
    const float* __restrict__ gns, const float* __restrict__ gnb,
    unsigned short* __restrict__ hnt) {
  __shared__ float tile[64][65];
  const int b  = blockIdx.z;
  const int c0 = blockIdx.y * 64, n0 = blockIdx.x * 64;
  const int tx = threadIdx.x & 63, ty = threadIdx.x >> 6;
  for (int i = 0; i < 16; ++i) {
    int cl = ty * 16 + i;
    int c  = c0 + cl;
    int g  = c >> 4;
    float mean = stats[(b * 32 + g) * 2];
    float rstd = stats[(b * 32 + g) * 2 + 1];
    float v = x[((size_t)(b * CDIM + c)) * NSP + n0 + tx];
    tile[cl][tx] = (v - mean) * rstd * gns[c] + gnb[c];
  }
  __syncthreads();
  for (int i = 0; i < 16; ++i) {
    int nl = ty * 16 + i;
    hnt[((size_t)(b * NSP + n0 + nl)) * CDIM + c0 + tx] = f2bf(tile[tx][nl]);
  }
}

// ---------------- fp32 -> bf16 weight conversion (4 weights, one launch) ----
__global__ __launch_bounds__(256) void weights_to_bf16(
    const float* __restrict__ w0, const float* __restrict__ w1,
    const float* __restrict__ w2, const float* __restrict__ w3,
    unsigned short* __restrict__ o0, unsigned short* __restrict__ o1,
    unsigned short* __restrict__ o2, unsigned short* __restrict__ o3) {
  const float* s; unsigned short* o;
  switch (blockIdx.y) {
    case 0: s = w0; o = o0; break;
    case 1: s = w1; o = o1; break;
    case 2: s = w2; o = o2; break;
    default: s = w3; o = o3; break;
  }
  int i = blockIdx.x * 256 + threadIdx.x;
  float4 v = ((const float4*)s)[i];
  u16x4 r = {f2bf(v.x), f2bf(v.y), f2bf(v.z), f2bf(v.w)};
  *(u16x4*)(o + (size_t)i * 4) = r;
}

// ---------------- NT GEMM 128x128 (R4-proven, for the small projections) ----
// BIAS_MODE: 0 none, 1 per-row bias[m], 2 per-col bias[n]
// OUT_MODE:  0 f32, 1 bf16
template <int BIAS_MODE, int OUT_MODE, int RESID>
__global__ __launch_bounds__(256) void gemm_nt(
    const unsigned short* __restrict__ A, const unsigned short* __restrict__ Bt,
    void* __restrict__ Dv, const float* __restrict__ bias,
    const float* __restrict__ resid,
    int M, int N, int K, float scale, long sA, long sB, long sD, long sR) {
  __shared__ unsigned short lsA[2][128 * 32];
  __shared__ unsigned short lsB[2][128 * 32];
  const int tid = threadIdx.x;
  const int w = tid >> 6, lane = tid & 63;
  const int wr = w >> 1, wc = w & 1;
  const int b = blockIdx.z;
  const int bm0 = blockIdx.y * 128, bn0 = blockIdx.x * 128;
  const unsigned short* Ab = A + (size_t)b * sA;
  const unsigned short* Bb = Bt + (size_t)b * sB;

  f32x4 acc[4][4] = {};
  const int r0  = w * 16 + (lane >> 2);
  const int kof = (lane & 3) * 8;
  const int fr  = lane & 15, kf = (lane >> 4) * 8;

  for (int it = 0; it < 2; ++it) {
    int row = it * 64 + r0;
    async_copy16(Ab + (size_t)(bm0 + row) * K + kof, &lsA[0][row * 32 + kof]);
    async_copy16(Bb + (size_t)(bn0 + row) * K + kof, &lsB[0][row * 32 + kof]);
  }
  __syncthreads();

  int cur = 0;
  for (int k0 = 0; k0 < K; k0 += 32) {
    const int nk = k0 + 32;
    if (nk < K) {
      for (int it = 0; it < 2; ++it) {
        int row = it * 64 + r0;
        async_copy16(Ab + (size_t)(bm0 + row) * K + nk + kof, &lsA[cur ^ 1][row * 32 + kof]);
        async_copy16(Bb + (size_t)(bn0 + row) * K + nk + kof, &lsB[cur ^ 1][row * 32 + kof]);
      }
    }
    bf16x8 af[4], bff[4];
    for (int i = 0; i < 4; ++i) {
      af[i]  = *(const bf16x8*)(&lsA[cur][(wr * 64 + i * 16 + fr) * 32 + kf]);
      bff[i] = *(const bf16x8*)(&lsB[cur][(wc * 64 + i * 16 + fr) * 32 + kf]);
    }
    for (int i = 0; i < 4; ++i)
      for (int j = 0; j < 4; ++j)
        acc[i][j] = __builtin_amdgcn_mfma_f32_16x16x32_bf16(af[i], bff[j], acc[i][j], 0, 0, 0);
    __syncthreads();
    cur ^= 1;
  }

  const int col_l = lane & 15, row_l = (lane >> 4) * 4;
  for (int i = 0; i < 4; ++i)
    for (int j = 0; j < 4; ++j) {
      int gr = bm0 + wr * 64 + i * 16 + row_l;
      int gc = bn0 + wc * 64 + j * 16 + col_l;
      for (int r = 0; r < 4; ++r) {
        float v = acc[i][j][r] * scale;
        if (BIAS_MODE == 1) v += bias[gr + r];
        if (BIAS_MODE == 2) v += bias[gc];
        if (RESID) v += resid[(size_t)b * sR + (size_t)(gr + r) * N + gc];
        if (OUT_MODE == 1)
          ((unsigned short*)Dv)[(size_t)b * sD + (size_t)(gr + r) * N + gc] = f2bf(v);
        else
          ((float*)Dv)[(size_t)b * sD + (size_t)(gr + r) * N + gc] = v;
      }
    }
}

// ---------------- NT GEMM 256x256, BK=64, 8 waves, phase-split ----------------
// D[M,N] = A[M,K] @ Bt[N,K]^T. OUT_MODE: 1 bf16, 2 fp16.
// SPLITK: blockIdx.z = split*NB+b, k in [split*kLen, +kLen), D offset z*M*N.
// EXPL: D = exp(acc*scale - M0), row-sums atomically into lsum[b*M+row].
// LDS: [2 buf][256 rows][64 k] for A and B = 128 KiB; 16B chunks XOR-swizzled
// by row&7 (source pre-swizzled for linear global_load_lds dest; reads apply
// the same XOR) -> 2-way bank aliasing max (free).
template <int OUT_MODE, int SPLITK, int EXPL>
__global__ __launch_bounds__(512, 2) void gemm256(
    const unsigned short* __restrict__ A, const unsigned short* __restrict__ Bt,
    void* __restrict__ Dv, float* __restrict__ lsum,
    int M, int N, int K, float scale, long sA, long sB, long sD, int kLen) {
  __shared__ unsigned short lsA[2][256 * 64];
  __shared__ unsigned short lsB[2][256 * 64];
  const int tid = threadIdx.x;
  const int wid = tid >> 6, lane = tid & 63;
  const int wm = wid >> 2, wn = wid & 3;      // 2 x 4 wave grid
  const int fr = lane & 15, kq = lane >> 4;
  const int b = SPLITK ? (blockIdx.z & 3) : blockIdx.z;
  const int bm0 = blockIdx.y * 256, bn0 = blockIdx.x * 256;
  const unsigned short* Ab = A + (size_t)b * sA;
  const unsigned short* Bb = Bt + (size_t)b * sB;
  const size_t dOff = SPLITK ? (size_t)blockIdx.z * (size_t)M * N
                             : (size_t)b * (size_t)sD;
  const int kStart = SPLITK ? (blockIdx.z >> 2) * kLen : 0;
  const int ntiles = (SPLITK ? kLen : K) >> 6;

  // stage part p of K-tile t into buf: p 0/1 = A halves, 2/3 = B halves.
  // thread t covers row (t>>3), chunk (t&7); source chunk pre-XOR'd so that
  // LDS phys chunk c holds global chunk c^(row&7).
  const int srow = tid >> 3;                 // 0..63
  const int schunk = (tid & 7) ^ (srow & 7); // pre-swizzled global chunk
  auto stage_part = [&](int t, int buf, int part) {
    const int k0 = kStart + t * 64;
    unsigned short* lds = (part < 2) ? &lsA[buf][0] : &lsB[buf][0];
    const unsigned short* g = (part < 2) ? Ab : Bb;
    const int tile0 = (part < 2) ? bm0 : bn0;
    const int h = part & 1;
#pragma unroll
    for (int i = 0; i < 2; ++i) {
      const int rl = h * 128 + i * 64 + srow;
      async_copy16(g + (size_t)(tile0 + rl) * K + k0 + schunk * 8,
                   lds + rl * 64 + (tid & 7) * 8);
    }
  };

  f32x4 acc[8][4] = {};
  // read-side swizzled chunk byte offsets (in shorts) for kh = 0,1
  const int cko0 = (((0 * 4 + kq) ^ (fr & 7)) * 8);
  const int cko1 = (((1 * 4 + kq) ^ (fr & 7)) * 8);
  const int arow = wm * 128 + fr;   // + mi*16
  const int brow = wn * 64 + fr;    // + ni*16

  // prologue: stage tile 0 fully, drain, barrier
#pragma unroll
  for (int p = 0; p < 4; ++p) stage_part(0, 0, p);
  asm volatile("s_waitcnt vmcnt(0)\ns_barrier" ::: "memory");

  for (int t = 0; t < ntiles; ++t) {
    const int cur = t & 1;
    const unsigned short* la = &lsA[cur][0];
    const unsigned short* lb = &lsB[cur][0];
    const bool pre = (t + 1 < ntiles);
#pragma unroll
    for (int q = 0; q < 4; ++q) {         // phases: (mh,nh)=(q&1, q>>1)
      if (pre) stage_part(t + 1, cur ^ 1, q);
      const int mh = q & 1, nh = q >> 1;
      bf16x8 af[4][2], bf[2][2];
#pragma unroll
      for (int i = 0; i < 4; ++i) {
        const int ra = (arow + (mh * 4 + i) * 16) * 64;
        af[i][0] = *(const bf16x8*)&la[ra + cko0];
        af[i][1] = *(const bf16x8*)&la[ra + cko1];
      }
#pragma unroll
      for (int j = 0; j < 2; ++j) {
        const int rb = (brow + (nh * 2 + j) * 16) * 64;
        bf[j][0] = *(const bf16x8*)&lb[rb + cko0];
        bf[j][1] = *(const bf16x8*)&lb[rb + cko1];
      }
      __builtin_amdgcn_s_setprio(1);
#pragma unroll
      for (int i = 0; i < 4; ++i)
#pragma unroll
        for (int j = 0; j < 2; ++j) {
          acc[mh*4+i][nh*2+j] = __builtin_amdgcn_mfma_f32_16x16x32_bf16(
              af[i][0], bf[j][0], acc[mh*4+i][nh*2+j], 0, 0, 0);
          acc[mh*4+i][nh*2+j] = __builtin_amdgcn_mfma_f32_16x16x32_bf16(
              af[i][1], bf[j][1], acc[mh*4+i][nh*2+j], 0, 0, 0);
        }
      __builtin_amdgcn_s_setprio(0);
      if (q < 3) asm volatile("s_barrier" ::: "memory");
    }
    // tile end: next tile's staging (8 loads) must be complete everywhere
    asm volatile("s_waitcnt vmcnt(0)\ns_barrier" ::: "memory");
  }

  // epilogue
  float rs[8][4];
  if (EXPL)
#pragma unroll
    for (int i = 0; i < 8; ++i)
#pragma unroll
      for (int r = 0; r < 4; ++r) rs[i][r] = 0.f;

#pragma unroll
  for (int mi = 0; mi < 8; ++mi)
#pragma unroll
    for (int ni = 0; ni < 4; ++ni) {
      const int gr = bm0 + wm * 128 + mi * 16 + kq * 4;
      const int gc = bn0 + wn * 64 + ni * 16 + fr;
#pragma unroll
      for (int r = 0; r < 4; ++r) {
        float v;
        if (EXPL) {
          v = __expf(fmaf(acc[mi][ni][r], scale, -M0));
          rs[mi][r] += v;
        } else {
          v = acc[mi][ni][r] * scale;
        }
        if (OUT_MODE == 1)
          ((unsigned short*)Dv)[dOff + (size_t)(gr + r) * N + gc] = f2bf(v);
        else
          ((_Float16*)Dv)[dOff + (size_t)(gr + r) * N + gc] = (_Float16)v;
      }
    }

  if (EXPL) {
#pragma unroll
    for (int mi = 0; mi < 8; ++mi)
#pragma unroll
      for (int r = 0; r < 4; ++r) {
        float v = rs[mi][r];
        v += __shfl_xor(v, 1); v += __shfl_xor(v, 2);
        v += __shfl_xor(v, 4); v += __shfl_xor(v, 8);
        if (fr == 0) {
          int gr = bm0 + wm * 128 + mi * 16 + kq * 4 + r;
          atomicAdd(&lsum[(size_t)b * M + gr], v);
        }
      }
  }
}

// ---------------- reduce: ot = (Op0 + Op1) / l  -> bf16 ----------------
__global__ __launch_bounds__(256) void reduce_div(const _Float16* __restrict__ Op,
                                                  const float* __restrict__ l,
                                                  unsigned short* __restrict__ ot) {
  const size_t stride = (size_t)NB * NSP * CDIM;  // elems per split
  size_t base = ((size_t)blockIdx.x * 256 + threadIdx.x) * 8;
  float linv = 1.f / l[base >> 9];  // row = base / 512
  h8 a = *(const h8*)(Op + base);
  h8 c = *(const h8*)(Op + stride + base);
  u16x4 o0, o1;
#pragma unroll
  for (int i = 0; i < 4; ++i) {
    o0[i] = f2bf(((float)a[i] + (float)c[i]) * linv);
    o1[i] = f2bf(((float)a[i + 4] + (float)c[i + 4]) * linv);
  }
  *(u16x4*)(ot + base) = o0;
  *(u16x4*)(ot + base + 4) = o1;
}

extern "C" void kernel_launch(void* const* d_in, const int* in_sizes, int n_in,
                              void* d_out, int out_size, void* d_ws, size_t ws_size,
                              hipStream_t stream) {
  const float* hs  = (const float*)d_in[0];
  const float* gns = (const float*)d_in[1];
  const float* gnb = (const float*)d_in[2];
  const float* wq  = (const float*)d_in[3];
  const float* bq  = (const float*)d_in[4];
  const float* wk  = (const float*)d_in[5];
  const float* bk  = (const float*)d_in[6];
  const float* wv  = (const float*)d_in[7];
  const float* bv  = (const float*)d_in[8];
  const float* wp  = (const float*)d_in[9];
  const float* bp  = (const float*)d_in[10];

  char* p = (char*)d_ws;
  unsigned short* wqb = (unsigned short*)p; p += (size_t)CDIM * CDIM * 2;
  unsigned short* wkb = (unsigned short*)p; p += (size_t)CDIM * CDIM * 2;
  unsigned short* wvb = (unsigned short*)p; p += (size_t)CDIM * CDIM * 2;
  unsigned short* wpb = (unsigned short*)p; p += (size_t)CDIM * CDIM * 2;
  const size_t bn = (size_t)NSP * CDIM;  // 2M elements per batch
  unsigned short* hnt = (unsigned short*)p; p += NB * bn * 2;   // also reused as ot
  unsigned short* qt  = (unsigned short*)p; p += NB * bn * 2;
  unsigned short* kt  = (unsigned short*)p; p += NB * bn * 2;
  unsigned short* vcn = (unsigned short*)p; p += NB * bn * 2;
  unsigned short* P   = (unsigned short*)p; p += (size_t)NB * NSP * NSP * 2;  // 128 MiB
  _Float16* Op = (_Float16*)p;  p += (size_t)2 * NB * bn * 2;   // 32 MiB (2 splits)
  float* lsum  = (float*)p;     p += (size_t)NB * NSP * 4;      // 64 KiB
  float* stats = (float*)p;     p += 256 * 4;
  unsigned short* ot = hnt;  // hnt dead after the QKV projections

  hipMemsetAsync(lsum, 0, (size_t)NB * NSP * 4, stream);
  weights_to_bf16<<<dim3(256, 4), 256, 0, stream>>>(wq, wk, wv, wp, wqb, wkb, wvb, wpb);
  gn_stats<<<128, 256, 0, stream>>>(hs, stats);
  norm_transpose<<<dim3(64, 8, 4), 256, 0, stream>>>(hs, stats, gns, gnb, hnt);

  const long sBN = (long)bn;
  const long sPP = (long)NSP * NSP;
  // Qt[b] (4096x512) = Hnt[b] @ Wq^T + bq (per-col)
  gemm_nt<2, 1, 0><<<dim3(4, 32, NB), 256, 0, stream>>>(
      hnt, wqb, qt, bq, nullptr, NSP, CDIM, CDIM, 1.f, sBN, 0, sBN, 0);
  gemm_nt<2, 1, 0><<<dim3(4, 32, NB), 256, 0, stream>>>(
      hnt, wkb, kt, bk, nullptr, NSP, CDIM, CDIM, 1.f, sBN, 0, sBN, 0);
  // Vcn[b] (512x4096) = Wv @ Hnt[b]^T + bv (per-row)
  gemm_nt<1, 1, 0><<<dim3(32, 4, NB), 256, 0, stream>>>(
      wvb, hnt, vcn, bv, nullptr, CDIM, NSP, CDIM, 1.f, 0, sBN, sBN, 0);

  // P[b] (4096x4096 bf16) = exp(Qt Kt^T * C^-0.5 - M0); lsum[b][i] += row sums
  const float sc = 0.044194173824159216f;  // 512^-0.5
  gemm256<1, 0, 1><<<dim3(16, 16, NB), 512, 0, stream>>>(
      qt, kt, P, lsum, NSP, NSP, CDIM, sc, sBN, sBN, sPP, 0);

  // PV split-K=2: Op[z] (4096x512 fp16) = P[b][:, ks:+2048] @ Vcn[b][:, same]^T
  gemm256<2, 1, 0><<<dim3(2, 16, 2 * NB), 512, 0, stream>>>(
      P, vcn, Op, nullptr, NSP, CDIM, NSP, 1.f, sPP, sBN, 0, NSP / 2);

  // ot (bf16) = (Op0 + Op1) / lsum
  reduce_div<<<4096, 256, 0, stream>>>(Op, lsum, ot);

  // out[b] (512x4096 fp32) = Wp @ Ot[b]^T + bp (per-row) + residual
  gemm_nt<1, 0, 1><<<dim3(32, 4, NB), 256, 0, stream>>>(
      wpb, ot, (float*)d_out, bp, hs, CDIM, NSP, CDIM, 1.f, 0, sBN, sBN, sBN);
}

// Round 7
// 366.644 us; speedup vs baseline: 1.1269x; 1.0247x over previous
//
#include <hip/hip_runtime.h>
#include <cstdint>
#include <cstddef>

// AttnBlock: B=4, C=512, H=W=64 (N=4096). All-fp32 I/O, bf16 MFMA internally.
// R7: gemm256 gets TRUE counted vmcnt (T4): staging split into 4 quadrant-
//     aligned parts; part q of tile t+1 issued at phase q of tile t; waits
//     vmcnt(4,4,4,6) retire exactly the part needed 4 phases after issue.
//     No vmcnt(0) in the main loop (peeled tail drains 4,2,0,0).

#define CDIM 512
#define NSP  4096
#define NB   4
#define M0   12.0f

using bf16x8 = __attribute__((ext_vector_type(8))) __bf16;
using f32x4  = __attribute__((ext_vector_type(4))) float;
using u16x4  = __attribute__((ext_vector_type(4))) unsigned short;
using h8     = __attribute__((ext_vector_type(8))) _Float16;

__device__ __forceinline__ unsigned short f2bf(float f) {
  unsigned int u = __float_as_uint(f);
  u += 0x7fffu + ((u >> 16) & 1u);
  return (unsigned short)(u >> 16);
}

__device__ __forceinline__ void async_copy16(const unsigned short* g, unsigned short* l) {
  __builtin_amdgcn_global_load_lds(
      (const __attribute__((address_space(1))) void*)g,
      (__attribute__((address_space(3))) void*)l, 16, 0, 0);
}

// ---------------- GroupNorm stats: one block per (b, group) ----------------
__global__ __launch_bounds__(256) void gn_stats(const float* __restrict__ x,
                                                float* __restrict__ stats) {
  const size_t base = (size_t)blockIdx.x * 65536;  // 16 ch * 4096, contiguous
  const float4* p = (const float4*)(x + base);
  float s = 0.f, ss = 0.f;
  for (int i = threadIdx.x; i < 16384; i += 256) {
    float4 v = p[i];
    s  += v.x + v.y + v.z + v.w;
    ss += v.x*v.x + v.y*v.y + v.z*v.z + v.w*v.w;
  }
  for (int off = 32; off; off >>= 1) {
    s  += __shfl_xor(s, off);
    ss += __shfl_xor(ss, off);
  }
  __shared__ float rs[4], rss[4];
  const int w = threadIdx.x >> 6;
  if ((threadIdx.x & 63) == 0) { rs[w] = s; rss[w] = ss; }
  __syncthreads();
  if (threadIdx.x == 0) {
    float S  = rs[0] + rs[1] + rs[2] + rs[3];
    float SS = rss[0] + rss[1] + rss[2] + rss[3];
    float mean = S * (1.f / 65536.f);
    float var  = SS * (1.f / 65536.f) - mean * mean;
    stats[2 * blockIdx.x]     = mean;
    stats[2 * blockIdx.x + 1] = rsqrtf(var + 1e-6f);
  }
}

// ------------- normalize + transpose: x(B,C,N) f32 -> Hnt(B,N,C) bf16 -------
__global__ __launch_bounds__(256) void norm_transpose(
    const float* __restrict__ x, const float* __restrict__ stats,
    const float* __restrict__ gns, const float* __restrict__ gnb,
    unsigned short* __restrict__ hnt) {
  __shared__ float tile[64][65];
  const int b  = blockIdx.z;
  const int c0 = blockIdx.y * 64, n0 = blockIdx.x * 64;
  const int tx = threadIdx.x & 63, ty = threadIdx.x >> 6;
  for (int i = 0; i < 16; ++i) {
    int cl = ty * 16 + i;
    int c  = c0 + cl;
    int g  = c >> 4;
    float mean = stats[(b * 32 + g) * 2];
    float rstd = stats[(b * 32 + g) * 2 + 1];
    float v = x[((size_t)(b * CDIM + c)) * NSP + n0 + tx];
    tile[cl][tx] = (v - mean) * rstd * gns[c] + gnb[c];
  }
  __syncthreads();
  for (int i = 0; i < 16; ++i) {
    int nl = ty * 16 + i;
    hnt[((size_t)(b * NSP + n0 + nl)) * CDIM + c0 + tx] = f2bf(tile[tx][nl]);
  }
}

// ---------------- fp32 -> bf16 weight conversion (4 weights, one launch) ----
__global__ __launch_bounds__(256) void weights_to_bf16(
    const float* __restrict__ w0, const float* __restrict__ w1,
    const float* __restrict__ w2, const float* __restrict__ w3,
    unsigned short* __restrict__ o0, unsigned short* __restrict__ o1,
    unsigned short* __restrict__ o2, unsigned short* __restrict__ o3) {
  const float* s; unsigned short* o;
  switch (blockIdx.y) {
    case 0: s = w0; o = o0; break;
    case 1: s = w1; o = o1; break;
    case 2: s = w2; o = o2; break;
    default: s = w3; o = o3; break;
  }
  int i = blockIdx.x * 256 + threadIdx.x;
  float4 v = ((const float4*)s)[i];
  u16x4 r = {f2bf(v.x), f2bf(v.y), f2bf(v.z), f2bf(v.w)};
  *(u16x4*)(o + (size_t)i * 4) = r;
}

// ---------------- NT GEMM 128x128 (R4-proven, for the small projections) ----
template <int BIAS_MODE, int OUT_MODE, int RESID>
__global__ __launch_bounds__(256) void gemm_nt(
    const unsigned short* __restrict__ A, const unsigned short* __restrict__ Bt,
    void* __restrict__ Dv, const float* __restrict__ bias,
    const float* __restrict__ resid,
    int M, int N, int K, float scale, long sA, long sB, long sD, long sR) {
  __shared__ unsigned short lsA[2][128 * 32];
  __shared__ unsigned short lsB[2][128 * 32];
  const int tid = threadIdx.x;
  const int w = tid >> 6, lane = tid & 63;
  const int wr = w >> 1, wc = w & 1;
  const int b = blockIdx.z;
  const int bm0 = blockIdx.y * 128, bn0 = blockIdx.x * 128;
  const unsigned short* Ab = A + (size_t)b * sA;
  const unsigned short* Bb = Bt + (size_t)b * sB;

  f32x4 acc[4][4] = {};
  const int r0  = w * 16 + (lane >> 2);
  const int kof = (lane & 3) * 8;
  const int fr  = lane & 15, kf = (lane >> 4) * 8;

  for (int it = 0; it < 2; ++it) {
    int row = it * 64 + r0;
    async_copy16(Ab + (size_t)(bm0 + row) * K + kof, &lsA[0][row * 32 + kof]);
    async_copy16(Bb + (size_t)(bn0 + row) * K + kof, &lsB[0][row * 32 + kof]);
  }
  __syncthreads();

  int cur = 0;
  for (int k0 = 0; k0 < K; k0 += 32) {
    const int nk = k0 + 32;
    if (nk < K) {
      for (int it = 0; it < 2; ++it) {
        int row = it * 64 + r0;
        async_copy16(Ab + (size_t)(bm0 + row) * K + nk + kof, &lsA[cur ^ 1][row * 32 + kof]);
        async_copy16(Bb + (size_t)(bn0 + row) * K + nk + kof, &lsB[cur ^ 1][row * 32 + kof]);
      }
    }
    bf16x8 af[4], bff[4];
    for (int i = 0; i < 4; ++i) {
      af[i]  = *(const bf16x8*)(&lsA[cur][(wr * 64 + i * 16 + fr) * 32 + kf]);
      bff[i] = *(const bf16x8*)(&lsB[cur][(wc * 64 + i * 16 + fr) * 32 + kf]);
    }
    for (int i = 0; i < 4; ++i)
      for (int j = 0; j < 4; ++j)
        acc[i][j] = __builtin_amdgcn_mfma_f32_16x16x32_bf16(af[i], bff[j], acc[i][j], 0, 0, 0);
    __syncthreads();
    cur ^= 1;
  }

  const int col_l = lane & 15, row_l = (lane >> 4) * 4;
  for (int i = 0; i < 4; ++i)
    for (int j = 0; j < 4; ++j) {
      int gr = bm0 + wr * 64 + i * 16 + row_l;
      int gc = bn0 + wc * 64 + j * 16 + col_l;
      for (int r = 0; r < 4; ++r) {
        float v = acc[i][j][r] * scale;
        if (BIAS_MODE == 1) v += bias[gr + r];
        if (BIAS_MODE == 2) v += bias[gc];
        if (RESID) v += resid[(size_t)b * sR + (size_t)(gr + r) * N + gc];
        if (OUT_MODE == 1)
          ((unsigned short*)Dv)[(size_t)b * sD + (size_t)(gr + r) * N + gc] = f2bf(v);
        else
          ((float*)Dv)[(size_t)b * sD + (size_t)(gr + r) * N + gc] = v;
      }
    }
}

// ---------------- NT GEMM 256x256, BK=64, 8 waves, counted-vmcnt pipeline ----
// Parts: 0 = A rows (bit6==0), 1 = B rows (bit5==0), 2 = A rows (bit6==1),
//        3 = B rows (bit5==1). Part q of tile t+1 issued at phase q of tile t.
// Phase quadrants: q0=(mh0,nh0) q1=(mh1,nh0) q2=(mh0,nh1) q3=(mh1,nh1).
// Waits {4,4,4,6}: each retires exactly the part first consumed this phase,
// issued 4 phases (~1 tile) earlier. Tail peels with {4,2,0,0}.
template <int OUT_MODE, int SPLITK, int EXPL>
__global__ __launch_bounds__(512, 2) void gemm256(
    const unsigned short* __restrict__ A, const unsigned short* __restrict__ Bt,
    void* __restrict__ Dv, float* __restrict__ lsum,
    int M, int N, int K, float scale, long sA, long sB, long sD, int kLen) {
  __shared__ unsigned short lsA[2][256 * 64];
  __shared__ unsigned short lsB[2][256 * 64];
  const int tid = threadIdx.x;
  const int wid = tid >> 6, lane = tid & 63;
  const int wm = wid >> 2, wn = wid & 3;      // 2 x 4 wave grid
  const int fr = lane & 15, kq = lane >> 4;
  const int b = SPLITK ? (blockIdx.z & 3) : blockIdx.z;
  const int bm0 = blockIdx.y * 256, bn0 = blockIdx.x * 256;
  const unsigned short* Ab = A + (size_t)b * sA;
  const unsigned short* Bb = Bt + (size_t)b * sB;
  const size_t dOff = SPLITK ? (size_t)blockIdx.z * (size_t)M * N
                             : (size_t)b * (size_t)sD;
  const int kStart = SPLITK ? (blockIdx.z >> 2) * kLen : 0;
  const int ntiles = (SPLITK ? kLen : K) >> 6;

  const int srow = tid >> 3;                 // 0..63
  const int schunk = (tid & 7) ^ (srow & 7); // pre-swizzled global chunk
  const int s5 = srow >> 5, sl = srow & 31;

  // stage part of K-tile t into buf (2 x 16B loads per thread)
  auto stage_part = [&](int t, int buf, int part) {
    const int k0 = kStart + t * 64;
    if (part == 0 || part == 2) {            // A rows with bit6 == part>>1
      const int mh = part >> 1;
#pragma unroll
      for (int i = 0; i < 2; ++i) {
        const int rl = i * 128 + mh * 64 + srow;
        async_copy16(Ab + (size_t)(bm0 + rl) * K + k0 + schunk * 8,
                     &lsA[buf][rl * 64 + (tid & 7) * 8]);
      }
    } else {                                 // B rows with bit5 == part>>1
      const int nh = part >> 1;
#pragma unroll
      for (int i = 0; i < 2; ++i) {
        const int rl = i * 128 + s5 * 64 + nh * 32 + sl;
        async_copy16(Bb + (size_t)(bn0 + rl) * K + k0 + schunk * 8,
                     &lsB[buf][rl * 64 + (tid & 7) * 8]);
      }
    }
  };

  f32x4 acc[8][4] = {};
  const int cko0 = (((0 * 4 + kq) ^ (fr & 7)) * 8);
  const int cko1 = (((1 * 4 + kq) ^ (fr & 7)) * 8);
  const int arow = wm * 128 + fr;
  const int brow = wn * 64 + fr;

#define PHASE(mh, nh, part, W, PRE)                                          \
  {                                                                          \
    asm volatile("s_waitcnt vmcnt(" W ")\n\ts_barrier" ::: "memory");        \
    if (PRE) stage_part(t + 1, nbuf, part);                                  \
    bf16x8 af[4][2], bg[2][2];                                               \
    _Pragma("unroll")                                                        \
    for (int i = 0; i < 4; ++i) {                                            \
      const int ra = (arow + ((mh) * 4 + i) * 16) * 64;                      \
      af[i][0] = *(const bf16x8*)&la[ra + cko0];                             \
      af[i][1] = *(const bf16x8*)&la[ra + cko1];                             \
    }                                                                        \
    _Pragma("unroll")                                                        \
    for (int j = 0; j < 2; ++j) {                                            \
      const int rb = (brow + ((nh) * 2 + j) * 16) * 64;                      \
      bg[j][0] = *(const bf16x8*)&lb[rb + cko0];                             \
      bg[j][1] = *(const bf16x8*)&lb[rb + cko1];                             \
    }                                                                        \
    __builtin_amdgcn_s_setprio(1);                                           \
    _Pragma("unroll")                                                        \
    for (int i = 0; i < 4; ++i)                                              \
      _Pragma("unroll")                                                      \
      for (int j = 0; j < 2; ++j) {                                          \
        acc[(mh)*4+i][(nh)*2+j] = __builtin_amdgcn_mfma_f32_16x16x32_bf16(   \
            af[i][0], bg[j][0], acc[(mh)*4+i][(nh)*2+j], 0, 0, 0);           \
        acc[(mh)*4+i][(nh)*2+j] = __builtin_amdgcn_mfma_f32_16x16x32_bf16(   \
            af[i][1], bg[j][1], acc[(mh)*4+i][(nh)*2+j], 0, 0, 0);           \
      }                                                                      \
    __builtin_amdgcn_s_setprio(0);                                           \
  }

  // prologue: all 4 parts of tile 0 (issue order 0,1,2,3 = wait retire order)
  stage_part(0, 0, 0); stage_part(0, 0, 1);
  stage_part(0, 0, 2); stage_part(0, 0, 3);

  for (int t = 0; t < ntiles - 1; ++t) {
    const int cur = t & 1, nbuf = cur ^ 1;
    const unsigned short* la = &lsA[cur][0];
    const unsigned short* lb = &lsB[cur][0];
    PHASE(0, 0, 0, "4", true)
    PHASE(1, 0, 1, "4", true)
    PHASE(0, 1, 2, "4", true)
    PHASE(1, 1, 3, "6", true)
  }
  {  // peeled tail: no prefetch, progressive drain
    const int t = ntiles - 1;
    const int cur = t & 1, nbuf = cur ^ 1; (void)nbuf;
    const unsigned short* la = &lsA[cur][0];
    const unsigned short* lb = &lsB[cur][0];
    PHASE(0, 0, 0, "4", false)
    PHASE(1, 0, 1, "2", false)
    PHASE(0, 1, 2, "0", false)
    PHASE(1, 1, 3, "0", false)
  }
#undef PHASE

  // epilogue
  float rs[8][4];
  if (EXPL)
#pragma unroll
    for (int i = 0; i < 8; ++i)
#pragma unroll
      for (int r = 0; r < 4; ++r) rs[i][r] = 0.f;

#pragma unroll
  for (int mi = 0; mi < 8; ++mi)
#pragma unroll
    for (int ni = 0; ni < 4; ++ni) {
      const int gr = bm0 + wm * 128 + mi * 16 + kq * 4;
      const int gc = bn0 + wn * 64 + ni * 16 + fr;
#pragma unroll
      for (int r = 0; r < 4; ++r) {
        float v;
        if (EXPL) {
          v = __expf(fmaf(acc[mi][ni][r], scale, -M0));
          rs[mi][r] += v;
        } else {
          v = acc[mi][ni][r] * scale;
        }
        if (OUT_MODE == 1)
          ((unsigned short*)Dv)[dOff + (size_t)(gr + r) * N + gc] = f2bf(v);
        else
          ((_Float16*)Dv)[dOff + (size_t)(gr + r) * N + gc] = (_Float16)v;
      }
    }

  if (EXPL) {
#pragma unroll
    for (int mi = 0; mi < 8; ++mi)
#pragma unroll
      for (int r = 0; r < 4; ++r) {
        float v = rs[mi][r];
        v += __shfl_xor(v, 1); v += __shfl_xor(v, 2);
        v += __shfl_xor(v, 4); v += __shfl_xor(v, 8);
        if (fr == 0) {
          int gr = bm0 + wm * 128 + mi * 16 + kq * 4 + r;
          atomicAdd(&lsum[(size_t)b * M + gr], v);
        }
      }
  }
}

// ---------------- reduce: ot = (Op0 + Op1) / l  -> bf16 ----------------
__global__ __launch_bounds__(256) void reduce_div(const _Float16* __restrict__ Op,
                                                  const float* __restrict__ l,
                                                  unsigned short* __restrict__ ot) {
  const size_t stride = (size_t)NB * NSP * CDIM;  // elems per split
  size_t base = ((size_t)blockIdx.x * 256 + threadIdx.x) * 8;
  float linv = 1.f / l[base >> 9];  // row = base / 512
  h8 a = *(const h8*)(Op + base);
  h8 c = *(const h8*)(Op + stride + base);
  u16x4 o0, o1;
#pragma unroll
  for (int i = 0; i < 4; ++i) {
    o0[i] = f2bf(((float)a[i] + (float)c[i]) * linv);
    o1[i] = f2bf(((float)a[i + 4] + (float)c[i + 4]) * linv);
  }
  *(u16x4*)(ot + base) = o0;
  *(u16x4*)(ot + base + 4) = o1;
}

extern "C" void kernel_launch(void* const* d_in, const int* in_sizes, int n_in,
                              void* d_out, int out_size, void* d_ws, size_t ws_size,
                              hipStream_t stream) {
  const float* hs  = (const float*)d_in[0];
  const float* gns = (const float*)d_in[1];
  const float* gnb = (const float*)d_in[2];
  const float* wq  = (const float*)d_in[3];
  const float* bq  = (const float*)d_in[4];
  const float* wk  = (const float*)d_in[5];
  const float* bk  = (const float*)d_in[6];
  const float* wv  = (const float*)d_in[7];
  const float* bv  = (const float*)d_in[8];
  const float* wp  = (const float*)d_in[9];
  const float* bp  = (const float*)d_in[10];

  char* p = (char*)d_ws;
  unsigned short* wqb = (unsigned short*)p; p += (size_t)CDIM * CDIM * 2;
  unsigned short* wkb = (unsigned short*)p; p += (size_t)CDIM * CDIM * 2;
  unsigned short* wvb = (unsigned short*)p; p += (size_t)CDIM * CDIM * 2;
  unsigned short* wpb = (unsigned short*)p; p += (size_t)CDIM * CDIM * 2;
  const size_t bn = (size_t)NSP * CDIM;  // 2M elements per batch
  unsigned short* hnt = (unsigned short*)p; p += NB * bn * 2;   // also reused as ot
  unsigned short* qt  = (unsigned short*)p; p += NB * bn * 2;
  unsigned short* kt  = (unsigned short*)p; p += NB * bn * 2;
  unsigned short* vcn = (unsigned short*)p; p += NB * bn * 2;
  unsigned short* P   = (unsigned short*)p; p += (size_t)NB * NSP * NSP * 2;  // 128 MiB
  _Float16* Op = (_Float16*)p;  p += (size_t)2 * NB * bn * 2;   // 32 MiB (2 splits)
  float* lsum  = (float*)p;     p += (size_t)NB * NSP * 4;      // 64 KiB
  float* stats = (float*)p;     p += 256 * 4;
  unsigned short* ot = hnt;  // hnt dead after the QKV projections

  hipMemsetAsync(lsum, 0, (size_t)NB * NSP * 4, stream);
  weights_to_bf16<<<dim3(256, 4), 256, 0, stream>>>(wq, wk, wv, wp, wqb, wkb, wvb, wpb);
  gn_stats<<<128, 256, 0, stream>>>(hs, stats);
  norm_transpose<<<dim3(64, 8, 4), 256, 0, stream>>>(hs, stats, gns, gnb, hnt);

  const long sBN = (long)bn;
  const long sPP = (long)NSP * NSP;
  // Qt[b] (4096x512) = Hnt[b] @ Wq^T + bq (per-col)
  gemm_nt<2, 1, 0><<<dim3(4, 32, NB), 256, 0, stream>>>(
      hnt, wqb, qt, bq, nullptr, NSP, CDIM, CDIM, 1.f, sBN, 0, sBN, 0);
  gemm_nt<2, 1, 0><<<dim3(4, 32, NB), 256, 0, stream>>>(
      hnt, wkb, kt, bk, nullptr, NSP, CDIM, CDIM, 1.f, sBN, 0, sBN, 0);
  // Vcn[b] (512x4096) = Wv @ Hnt[b]^T + bv (per-row)
  gemm_nt<1, 1, 0><<<dim3(32, 4, NB), 256, 0, stream>>>(
      wvb, hnt, vcn, bv, nullptr, CDIM, NSP, CDIM, 1.f, 0, sBN, sBN, 0);

  // P[b] (4096x4096 bf16) = exp(Qt Kt^T * C^-0.5 - M0); lsum[b][i] += row sums
  const float sc = 0.044194173824159216f;  // 512^-0.5
  gemm256<1, 0, 1><<<dim3(16, 16, NB), 512, 0, stream>>>(
      qt, kt, P, lsum, NSP, NSP, CDIM, sc, sBN, sBN, sPP, 0);

  // PV split-K=2: Op[z] (4096x512 fp16) = P[b][:, ks:+2048] @ Vcn[b][:, same]^T
  gemm256<2, 1, 0><<<dim3(2, 16, 2 * NB), 512, 0, stream>>>(
      P, vcn, Op, nullptr, NSP, CDIM, NSP, 1.f, sPP, sBN, 0, NSP / 2);

  // ot (bf16) = (Op0 + Op1) / lsum
  reduce_div<<<4096, 256, 0, stream>>>(Op, lsum, ot);

  // out[b] (512x4096 fp32) = Wp @ Ot[b]^T + bp (per-row) + residual
  gemm_nt<1, 0, 1><<<dim3(32, 4, NB), 256, 0, stream>>>(
      wpb, ot, (float*)d_out, bp, hs, CDIM, NSP, CDIM, 1.f, 0, sBN, sBN, sBN);
}

// Round 8
// 336.296 us; speedup vs baseline: 1.2286x; 1.0902x over previous
//
#include <hip/hip_runtime.h>
#include <cstdint>
#include <cstddef>

// AttnBlock: B=4, C=512, H=W=64 (N=4096). All-fp32 I/O, bf16 MFMA internally.
// R8: gemm256 inner loop 4 phases -> 2 phases per K-tile with B-fragments
//     register-resident across the tile: LDS reads per wave per tile cut
//     48 -> 24 ds_read_b128 (the R6/R7 structure was LDS-BW-bound at ~40%
//     ceiling). Counted waits re-derived: issue order p0,p1,p3,p2; waits
//     A=vmcnt(2), B=vmcnt(4); tail 2,0.

#define CDIM 512
#define NSP  4096
#define NB   4
#define M0   12.0f

using bf16x8 = __attribute__((ext_vector_type(8))) __bf16;
using f32x4  = __attribute__((ext_vector_type(4))) float;
using u16x4  = __attribute__((ext_vector_type(4))) unsigned short;
using h8     = __attribute__((ext_vector_type(8))) _Float16;

__device__ __forceinline__ unsigned short f2bf(float f) {
  unsigned int u = __float_as_uint(f);
  u += 0x7fffu + ((u >> 16) & 1u);
  return (unsigned short)(u >> 16);
}

__device__ __forceinline__ void async_copy16(const unsigned short* g, unsigned short* l) {
  __builtin_amdgcn_global_load_lds(
      (const __attribute__((address_space(1))) void*)g,
      (__attribute__((address_space(3))) void*)l, 16, 0, 0);
}

// ---------------- GroupNorm stats: one block per (b, group) ----------------
__global__ __launch_bounds__(256) void gn_stats(const float* __restrict__ x,
                                                float* __restrict__ stats) {
  const size_t base = (size_t)blockIdx.x * 65536;  // 16 ch * 4096, contiguous
  const float4* p = (const float4*)(x + base);
  float s = 0.f, ss = 0.f;
  for (int i = threadIdx.x; i < 16384; i += 256) {
    float4 v = p[i];
    s  += v.x + v.y + v.z + v.w;
    ss += v.x*v.x + v.y*v.y + v.z*v.z + v.w*v.w;
  }
  for (int off = 32; off; off >>= 1) {
    s  += __shfl_xor(s, off);
    ss += __shfl_xor(ss, off);
  }
  __shared__ float rs[4], rss[4];
  const int w = threadIdx.x >> 6;
  if ((threadIdx.x & 63) == 0) { rs[w] = s; rss[w] = ss; }
  __syncthreads();
  if (threadIdx.x == 0) {
    float S  = rs[0] + rs[1] + rs[2] + rs[3];
    float SS = rss[0] + rss[1] + rss[2] + rss[3];
    float mean = S * (1.f / 65536.f);
    float var  = SS * (1.f / 65536.f) - mean * mean;
    stats[2 * blockIdx.x]     = mean;
    stats[2 * blockIdx.x + 1] = rsqrtf(var + 1e-6f);
  }
}

// ------------- normalize + transpose: x(B,C,N) f32 -> Hnt(B,N,C) bf16 -------
__global__ __launch_bounds__(256) void norm_transpose(
    const float* __restrict__ x, const float* __restrict__ stats,
    const float* __restrict__ gns, const float* __restrict__ gnb,
    unsigned short* __restrict__ hnt) {
  __shared__ float tile[64][65];
  const int b  = blockIdx.z;
  const int c0 = blockIdx.y * 64, n0 = blockIdx.x * 64;
  const int tx = threadIdx.x & 63, ty = threadIdx.x >> 6;
  for (int i = 0; i < 16; ++i) {
    int cl = ty * 16 + i;
    int c  = c0 + cl;
    int g  = c >> 4;
    float mean = stats[(b * 32 + g) * 2];
    float rstd = stats[(b * 32 + g) * 2 + 1];
    float v = x[((size_t)(b * CDIM + c)) * NSP + n0 + tx];
    tile[cl][tx] = (v - mean) * rstd * gns[c] + gnb[c];
  }
  __syncthreads();
  for (int i = 0; i < 16; ++i) {
    int nl = ty * 16 + i;
    hnt[((size_t)(b * NSP + n0 + nl)) * CDIM + c0 + tx] = f2bf(tile[tx][nl]);
  }
}

// ---------------- fp32 -> bf16 weight conversion (4 weights, one launch) ----
__global__ __launch_bounds__(256) void weights_to_bf16(
    const float* __restrict__ w0, const float* __restrict__ w1,
    const float* __restrict__ w2, const float* __restrict__ w3,
    unsigned short* __restrict__ o0, unsigned short* __restrict__ o1,
    unsigned short* __restrict__ o2, unsigned short* __restrict__ o3) {
  const float* s; unsigned short* o;
  switch (blockIdx.y) {
    case 0: s = w0; o = o0; break;
    case 1: s = w1; o = o1; break;
    case 2: s = w2; o = o2; break;
    default: s = w3; o = o3; break;
  }
  int i = blockIdx.x * 256 + threadIdx.x;
  float4 v = ((const float4*)s)[i];
  u16x4 r = {f2bf(v.x), f2bf(v.y), f2bf(v.z), f2bf(v.w)};
  *(u16x4*)(o + (size_t)i * 4) = r;
}

// ---------------- NT GEMM 128x128 (R4-proven, for the small projections) ----
template <int BIAS_MODE, int OUT_MODE, int RESID>
__global__ __launch_bounds__(256) void gemm_nt(
    const unsigned short* __restrict__ A, const unsigned short* __restrict__ Bt,
    void* __restrict__ Dv, const float* __restrict__ bias,
    const float* __restrict__ resid,
    int M, int N, int K, float scale, long sA, long sB, long sD, long sR) {
  __shared__ unsigned short lsA[2][128 * 32];
  __shared__ unsigned short lsB[2][128 * 32];
  const int tid = threadIdx.x;
  const int w = tid >> 6, lane = tid & 63;
  const int wr = w >> 1, wc = w & 1;
  const int b = blockIdx.z;
  const int bm0 = blockIdx.y * 128, bn0 = blockIdx.x * 128;
  const unsigned short* Ab = A + (size_t)b * sA;
  const unsigned short* Bb = Bt + (size_t)b * sB;

  f32x4 acc[4][4] = {};
  const int r0  = w * 16 + (lane >> 2);
  const int kof = (lane & 3) * 8;
  const int fr  = lane & 15, kf = (lane >> 4) * 8;

  for (int it = 0; it < 2; ++it) {
    int row = it * 64 + r0;
    async_copy16(Ab + (size_t)(bm0 + row) * K + kof, &lsA[0][row * 32 + kof]);
    async_copy16(Bb + (size_t)(bn0 + row) * K + kof, &lsB[0][row * 32 + kof]);
  }
  __syncthreads();

  int cur = 0;
  for (int k0 = 0; k0 < K; k0 += 32) {
    const int nk = k0 + 32;
    if (nk < K) {
      for (int it = 0; it < 2; ++it) {
        int row = it * 64 + r0;
        async_copy16(Ab + (size_t)(bm0 + row) * K + nk + kof, &lsA[cur ^ 1][row * 32 + kof]);
        async_copy16(Bb + (size_t)(bn0 + row) * K + nk + kof, &lsB[cur ^ 1][row * 32 + kof]);
      }
    }
    bf16x8 af[4], bff[4];
    for (int i = 0; i < 4; ++i) {
      af[i]  = *(const bf16x8*)(&lsA[cur][(wr * 64 + i * 16 + fr) * 32 + kf]);
      bff[i] = *(const bf16x8*)(&lsB[cur][(wc * 64 + i * 16 + fr) * 32 + kf]);
    }
    for (int i = 0; i < 4; ++i)
      for (int j = 0; j < 4; ++j)
        acc[i][j] = __builtin_amdgcn_mfma_f32_16x16x32_bf16(af[i], bff[j], acc[i][j], 0, 0, 0);
    __syncthreads();
    cur ^= 1;
  }

  const int col_l = lane & 15, row_l = (lane >> 4) * 4;
  for (int i = 0; i < 4; ++i)
    for (int j = 0; j < 4; ++j) {
      int gr = bm0 + wr * 64 + i * 16 + row_l;
      int gc = bn0 + wc * 64 + j * 16 + col_l;
      for (int r = 0; r < 4; ++r) {
        float v = acc[i][j][r] * scale;
        if (BIAS_MODE == 1) v += bias[gr + r];
        if (BIAS_MODE == 2) v += bias[gc];
        if (RESID) v += resid[(size_t)b * sR + (size_t)(gr + r) * N + gc];
        if (OUT_MODE == 1)
          ((unsigned short*)Dv)[(size_t)b * sD + (size_t)(gr + r) * N + gc] = f2bf(v);
        else
          ((float*)Dv)[(size_t)b * sD + (size_t)(gr + r) * N + gc] = v;
      }
    }
}

// ---------------- NT GEMM 256x256, BK=64, 8 waves, 2-phase, B-resident ----
// Parts: 0 = A rows bit6==0 (mh0), 2 = A rows bit6==1 (mh1),
//        1 = B rows bit5==0 (nh0), 3 = B rows bit5==1 (nh1).
// Issue order per tile: p0,p1,p3,p2 (prologue and prefetch alike).
// Phase A: wait vmcnt(2) [needs p0,p1,p3], stage next p0,p1,
//          read B-all (8, kept resident) + A-mh0 (8), 32 MFMA.
// Phase B: wait vmcnt(4) [needs p2; 4 newer in flight], stage next p3,p2,
//          read A-mh1 (8), 32 MFMA reusing B regs.
// Tail waits: 2, 0. LDS reads/wave/tile: 24 (floor) vs 48 in R7.
template <int OUT_MODE, int SPLITK, int EXPL>
__global__ __launch_bounds__(512, 2) void gemm256(
    const unsigned short* __restrict__ A, const unsigned short* __restrict__ Bt,
    void* __restrict__ Dv, float* __restrict__ lsum,
    int M, int N, int K, float scale, long sA, long sB, long sD, int kLen) {
  __shared__ unsigned short lsA[2][256 * 64];
  __shared__ unsigned short lsB[2][256 * 64];
  const int tid = threadIdx.x;
  const int wid = tid >> 6, lane = tid & 63;
  const int wm = wid >> 2, wn = wid & 3;      // 2 x 4 wave grid
  const int fr = lane & 15, kq = lane >> 4;
  const int b = SPLITK ? (blockIdx.z & 3) : blockIdx.z;
  const int bm0 = blockIdx.y * 256, bn0 = blockIdx.x * 256;
  const unsigned short* Ab = A + (size_t)b * sA;
  const unsigned short* Bb = Bt + (size_t)b * sB;
  const size_t dOff = SPLITK ? (size_t)blockIdx.z * (size_t)M * N
                             : (size_t)b * (size_t)sD;
  const int kStart = SPLITK ? (blockIdx.z >> 2) * kLen : 0;
  const int ntiles = (SPLITK ? kLen : K) >> 6;

  const int srow = tid >> 3;                 // 0..63
  const int schunk = (tid & 7) ^ (srow & 7); // pre-swizzled global chunk
  const int s5 = srow >> 5, sl = srow & 31;

  auto stage_part = [&](int t, int buf, int part) {
    const int k0 = kStart + t * 64;
    if (part == 0 || part == 2) {            // A rows with bit6 == part>>1
      const int mh = part >> 1;
#pragma unroll
      for (int i = 0; i < 2; ++i) {
        const int rl = i * 128 + mh * 64 + srow;
        async_copy16(Ab + (size_t)(bm0 + rl) * K + k0 + schunk * 8,
                     &lsA[buf][rl * 64 + (tid & 7) * 8]);
      }
    } else {                                 // B rows with bit5 == part>>1
      const int nh = part >> 1;
#pragma unroll
      for (int i = 0; i < 2; ++i) {
        const int rl = i * 128 + s5 * 64 + nh * 32 + sl;
        async_copy16(Bb + (size_t)(bn0 + rl) * K + k0 + schunk * 8,
                     &lsB[buf][rl * 64 + (tid & 7) * 8]);
      }
    }
  };

  f32x4 acc[8][4] = {};
  const int cko0 = (((0 * 4 + kq) ^ (fr & 7)) * 8);
  const int cko1 = (((1 * 4 + kq) ^ (fr & 7)) * 8);
  const int arow = wm * 128 + fr;
  const int brow = wn * 64 + fr;

  // prologue: tile 0 in issue order p0,p1,p3,p2
  stage_part(0, 0, 0); stage_part(0, 0, 1);
  stage_part(0, 0, 3); stage_part(0, 0, 2);

  for (int t = 0; t < ntiles; ++t) {
    const int cur = t & 1, nbuf = cur ^ 1;
    const unsigned short* la = &lsA[cur][0];
    const unsigned short* lb = &lsB[cur][0];
    const bool pre = (t + 1 < ntiles);

    bf16x8 bgr[4][2];  // B resident for the whole tile
    bf16x8 af[4][2];

    // ---- phase A: mh=0, all n ----
    asm volatile("s_waitcnt vmcnt(2)\n\ts_barrier" ::: "memory");
    if (pre) { stage_part(t + 1, nbuf, 0); stage_part(t + 1, nbuf, 1); }
#pragma unroll
    for (int j = 0; j < 4; ++j) {
      const int rb = (brow + j * 16) * 64;
      bgr[j][0] = *(const bf16x8*)&lb[rb + cko0];
      bgr[j][1] = *(const bf16x8*)&lb[rb + cko1];
    }
#pragma unroll
    for (int i = 0; i < 4; ++i) {
      const int ra = (arow + i * 16) * 64;
      af[i][0] = *(const bf16x8*)&la[ra + cko0];
      af[i][1] = *(const bf16x8*)&la[ra + cko1];
    }
    __builtin_amdgcn_s_setprio(1);
#pragma unroll
    for (int i = 0; i < 4; ++i)
#pragma unroll
      for (int j = 0; j < 4; ++j) {
        acc[i][j] = __builtin_amdgcn_mfma_f32_16x16x32_bf16(af[i][0], bgr[j][0], acc[i][j], 0, 0, 0);
        acc[i][j] = __builtin_amdgcn_mfma_f32_16x16x32_bf16(af[i][1], bgr[j][1], acc[i][j], 0, 0, 0);
      }
    __builtin_amdgcn_s_setprio(0);

    // ---- phase B: mh=1, all n (B regs reused) ----
    if (pre) asm volatile("s_waitcnt vmcnt(4)\n\ts_barrier" ::: "memory");
    else     asm volatile("s_waitcnt vmcnt(0)\n\ts_barrier" ::: "memory");
    if (pre) { stage_part(t + 1, nbuf, 3); stage_part(t + 1, nbuf, 2); }
#pragma unroll
    for (int i = 0; i < 4; ++i) {
      const int ra = (arow + 64 + i * 16) * 64;
      af[i][0] = *(const bf16x8*)&la[ra + cko0];
      af[i][1] = *(const bf16x8*)&la[ra + cko1];
    }
    __builtin_amdgcn_s_setprio(1);
#pragma unroll
    for (int i = 0; i < 4; ++i)
#pragma unroll
      for (int j = 0; j < 4; ++j) {
        acc[4 + i][j] = __builtin_amdgcn_mfma_f32_16x16x32_bf16(af[i][0], bgr[j][0], acc[4 + i][j], 0, 0, 0);
        acc[4 + i][j] = __builtin_amdgcn_mfma_f32_16x16x32_bf16(af[i][1], bgr[j][1], acc[4 + i][j], 0, 0, 0);
      }
    __builtin_amdgcn_s_setprio(0);
  }

  // epilogue
  float rs[8][4];
  if (EXPL)
#pragma unroll
    for (int i = 0; i < 8; ++i)
#pragma unroll
      for (int r = 0; r < 4; ++r) rs[i][r] = 0.f;

#pragma unroll
  for (int mi = 0; mi < 8; ++mi)
#pragma unroll
    for (int ni = 0; ni < 4; ++ni) {
      const int gr = bm0 + wm * 128 + mi * 16 + kq * 4;
      const int gc = bn0 + wn * 64 + ni * 16 + fr;
#pragma unroll
      for (int r = 0; r < 4; ++r) {
        float v;
        if (EXPL) {
          v = __expf(fmaf(acc[mi][ni][r], scale, -M0));
          rs[mi][r] += v;
        } else {
          v = acc[mi][ni][r] * scale;
        }
        if (OUT_MODE == 1)
          ((unsigned short*)Dv)[dOff + (size_t)(gr + r) * N + gc] = f2bf(v);
        else
          ((_Float16*)Dv)[dOff + (size_t)(gr + r) * N + gc] = (_Float16)v;
      }
    }

  if (EXPL) {
#pragma unroll
    for (int mi = 0; mi < 8; ++mi)
#pragma unroll
      for (int r = 0; r < 4; ++r) {
        float v = rs[mi][r];
        v += __shfl_xor(v, 1); v += __shfl_xor(v, 2);
        v += __shfl_xor(v, 4); v += __shfl_xor(v, 8);
        if (fr == 0) {
          int gr = bm0 + wm * 128 + mi * 16 + kq * 4 + r;
          atomicAdd(&lsum[(size_t)b * M + gr], v);
        }
      }
  }
}

// ---------------- reduce: ot = (Op0 + Op1) / l  -> bf16 ----------------
__global__ __launch_bounds__(256) void reduce_div(const _Float16* __restrict__ Op,
                                                  const float* __restrict__ l,
                                                  unsigned short* __restrict__ ot) {
  const size_t stride = (size_t)NB * NSP * CDIM;  // elems per split
  size_t base = ((size_t)blockIdx.x * 256 + threadIdx.x) * 8;
  float linv = 1.f / l[base >> 9];  // row = base / 512
  h8 a = *(const h8*)(Op + base);
  h8 c = *(const h8*)(Op + stride + base);
  u16x4 o0, o1;
#pragma unroll
  for (int i = 0; i < 4; ++i) {
    o0[i] = f2bf(((float)a[i] + (float)c[i]) * linv);
    o1[i] = f2bf(((float)a[i + 4] + (float)c[i + 4]) * linv);
  }
  *(u16x4*)(ot + base) = o0;
  *(u16x4*)(ot + base + 4) = o1;
}

extern "C" void kernel_launch(void* const* d_in, const int* in_sizes, int n_in,
                              void* d_out, int out_size, void* d_ws, size_t ws_size,
                              hipStream_t stream) {
  const float* hs  = (const float*)d_in[0];
  const float* gns = (const float*)d_in[1];
  const float* gnb = (const float*)d_in[2];
  const float* wq  = (const float*)d_in[3];
  const float* bq  = (const float*)d_in[4];
  const float* wk  = (const float*)d_in[5];
  const float* bk  = (const float*)d_in[6];
  const float* wv  = (const float*)d_in[7];
  const float* bv  = (const float*)d_in[8];
  const float* wp  = (const float*)d_in[9];
  const float* bp  = (const float*)d_in[10];

  char* p = (char*)d_ws;
  unsigned short* wqb = (unsigned short*)p; p += (size_t)CDIM * CDIM * 2;
  unsigned short* wkb = (unsigned short*)p; p += (size_t)CDIM * CDIM * 2;
  unsigned short* wvb = (unsigned short*)p; p += (size_t)CDIM * CDIM * 2;
  unsigned short* wpb = (unsigned short*)p; p += (size_t)CDIM * CDIM * 2;
  const size_t bn = (size_t)NSP * CDIM;  // 2M elements per batch
  unsigned short* hnt = (unsigned short*)p; p += NB * bn * 2;   // also reused as ot
  unsigned short* qt  = (unsigned short*)p; p += NB * bn * 2;
  unsigned short* kt  = (unsigned short*)p; p += NB * bn * 2;
  unsigned short* vcn = (unsigned short*)p; p += NB * bn * 2;
  unsigned short* P   = (unsigned short*)p; p += (size_t)NB * NSP * NSP * 2;  // 128 MiB
  _Float16* Op = (_Float16*)p;  p += (size_t)2 * NB * bn * 2;   // 32 MiB (2 splits)
  float* lsum  = (float*)p;     p += (size_t)NB * NSP * 4;      // 64 KiB
  float* stats = (float*)p;     p += 256 * 4;
  unsigned short* ot = hnt;  // hnt dead after the QKV projections

  hipMemsetAsync(lsum, 0, (size_t)NB * NSP * 4, stream);
  weights_to_bf16<<<dim3(256, 4), 256, 0, stream>>>(wq, wk, wv, wp, wqb, wkb, wvb, wpb);
  gn_stats<<<128, 256, 0, stream>>>(hs, stats);
  norm_transpose<<<dim3(64, 8, 4), 256, 0, stream>>>(hs, stats, gns, gnb, hnt);

  const long sBN = (long)bn;
  const long sPP = (long)NSP * NSP;
  // Qt[b] (4096x512) = Hnt[b] @ Wq^T + bq (per-col)
  gemm_nt<2, 1, 0><<<dim3(4, 32, NB), 256, 0, stream>>>(
      hnt, wqb, qt, bq, nullptr, NSP, CDIM, CDIM, 1.f, sBN, 0, sBN, 0);
  gemm_nt<2, 1, 0><<<dim3(4, 32, NB), 256, 0, stream>>>(
      hnt, wkb, kt, bk, nullptr, NSP, CDIM, CDIM, 1.f, sBN, 0, sBN, 0);
  // Vcn[b] (512x4096) = Wv @ Hnt[b]^T + bv (per-row)
  gemm_nt<1, 1, 0><<<dim3(32, 4, NB), 256, 0, stream>>>(
      wvb, hnt, vcn, bv, nullptr, CDIM, NSP, CDIM, 1.f, 0, sBN, sBN, 0);

  // P[b] (4096x4096 bf16) = exp(Qt Kt^T * C^-0.5 - M0); lsum[b][i] += row sums
  const float sc = 0.044194173824159216f;  // 512^-0.5
  gemm256<1, 0, 1><<<dim3(16, 16, NB), 512, 0, stream>>>(
      qt, kt, P, lsum, NSP, NSP, CDIM, sc, sBN, sBN, sPP, 0);

  // PV split-K=2: Op[z] (4096x512 fp16) = P[b][:, ks:+2048] @ Vcn[b][:, same]^T
  gemm256<2, 1, 0><<<dim3(2, 16, 2 * NB), 512, 0, stream>>>(
      P, vcn, Op, nullptr, NSP, CDIM, NSP, 1.f, sPP, sBN, 0, NSP / 2);

  // ot (bf16) = (Op0 + Op1) / lsum
  reduce_div<<<4096, 256, 0, stream>>>(Op, lsum, ot);

  // out[b] (512x4096 fp32) = Wp @ Ot[b]^T + bp (per-row) + residual
  gemm_nt<1, 0, 1><<<dim3(32, 4, NB), 256, 0, stream>>>(
      wpb, ot, (float*)d_out, bp, hs, CDIM, NSP, CDIM, 1.f, 0, sBN, sBN, sBN);
}

// Round 9
// 318.331 us; speedup vs baseline: 1.2979x; 1.0564x over previous
//
#include <hip/hip_runtime.h>
#include <cstdint>
#include <cstddef>

// AttnBlock: B=4, C=512, H=W=64 (N=4096). All-fp32 I/O, bf16 MFMA internally.
// R9: gemm256 -> faithful m201-style phase schedule: 4 phases/K-tile, each
//     {ds_read frags -> stage 1 part -> s_barrier -> setprio+16 MFMA -> s_barrier},
//     snake operand reuse (A0 resident, B carried), counted vmcnt(2) waits
//     placed one phase before the data is read. Never drain-0 in steady state.

#define CDIM 512
#define NSP  4096
#define NB   4
#define M0   12.0f

using bf16x8 = __attribute__((ext_vector_type(8))) __bf16;
using f32x4  = __attribute__((ext_vector_type(4))) float;
using u16x4  = __attribute__((ext_vector_type(4))) unsigned short;
using h8     = __attribute__((ext_vector_type(8))) _Float16;

__device__ __forceinline__ unsigned short f2bf(float f) {
  unsigned int u = __float_as_uint(f);
  u += 0x7fffu + ((u >> 16) & 1u);
  return (unsigned short)(u >> 16);
}

__device__ __forceinline__ void async_copy16(const unsigned short* g, unsigned short* l) {
  __builtin_amdgcn_global_load_lds(
      (const __attribute__((address_space(1))) void*)g,
      (__attribute__((address_space(3))) void*)l, 16, 0, 0);
}

// ---------------- GroupNorm stats: one block per (b, group) ----------------
__global__ __launch_bounds__(256) void gn_stats(const float* __restrict__ x,
                                                float* __restrict__ stats) {
  const size_t base = (size_t)blockIdx.x * 65536;  // 16 ch * 4096, contiguous
  const float4* p = (const float4*)(x + base);
  float s = 0.f, ss = 0.f;
  for (int i = threadIdx.x; i < 16384; i += 256) {
    float4 v = p[i];
    s  += v.x + v.y + v.z + v.w;
    ss += v.x*v.x + v.y*v.y + v.z*v.z + v.w*v.w;
  }
  for (int off = 32; off; off >>= 1) {
    s  += __shfl_xor(s, off);
    ss += __shfl_xor(ss, off);
  }
  __shared__ float rs[4], rss[4];
  const int w = threadIdx.x >> 6;
  if ((threadIdx.x & 63) == 0) { rs[w] = s; rss[w] = ss; }
  __syncthreads();
  if (threadIdx.x == 0) {
    float S  = rs[0] + rs[1] + rs[2] + rs[3];
    float SS = rss[0] + rss[1] + rss[2] + rss[3];
    float mean = S * (1.f / 65536.f);
    float var  = SS * (1.f / 65536.f) - mean * mean;
    stats[2 * blockIdx.x]     = mean;
    stats[2 * blockIdx.x + 1] = rsqrtf(var + 1e-6f);
  }
}

// ------------- normalize + transpose: x(B,C,N) f32 -> Hnt(B,N,C) bf16 -------
__global__ __launch_bounds__(256) void norm_transpose(
    const float* __restrict__ x, const float* __restrict__ stats,
    const float* __restrict__ gns, const float* __restrict__ gnb,
    unsigned short* __restrict__ hnt) {
  __shared__ float tile[64][65];
  const int b  = blockIdx.z;
  const int c0 = blockIdx.y * 64, n0 = blockIdx.x * 64;
  const int tx = threadIdx.x & 63, ty = threadIdx.x >> 6;
  for (int i = 0; i < 16; ++i) {
    int cl = ty * 16 + i;
    int c  = c0 + cl;
    int g  = c >> 4;
    float mean = stats[(b * 32 + g) * 2];
    float rstd = stats[(b * 32 + g) * 2 + 1];
    float v = x[((size_t)(b * CDIM + c)) * NSP + n0 + tx];
    tile[cl][tx] = (v - mean) * rstd * gns[c] + gnb[c];
  }
  __syncthreads();
  for (int i = 0; i < 16; ++i) {
    int nl = ty * 16 + i;
    hnt[((size_t)(b * NSP + n0 + nl)) * CDIM + c0 + tx] = f2bf(tile[tx][nl]);
  }
}

// ---------------- fp32 -> bf16 weight conversion (4 weights, one launch) ----
__global__ __launch_bounds__(256) void weights_to_bf16(
    const float* __restrict__ w0, const float* __restrict__ w1,
    const float* __restrict__ w2, const float* __restrict__ w3,
    unsigned short* __restrict__ o0, unsigned short* __restrict__ o1,
    unsigned short* __restrict__ o2, unsigned short* __restrict__ o3) {
  const float* s; unsigned short* o;
  switch (blockIdx.y) {
    case 0: s = w0; o = o0; break;
    case 1: s = w1; o = o1; break;
    case 2: s = w2; o = o2; break;
    default: s = w3; o = o3; break;
  }
  int i = blockIdx.x * 256 + threadIdx.x;
  float4 v = ((const float4*)s)[i];
  u16x4 r = {f2bf(v.x), f2bf(v.y), f2bf(v.z), f2bf(v.w)};
  *(u16x4*)(o + (size_t)i * 4) = r;
}

// ---------------- NT GEMM 128x128 (R4-proven, for the small projections) ----
template <int BIAS_MODE, int OUT_MODE, int RESID>
__global__ __launch_bounds__(256) void gemm_nt(
    const unsigned short* __restrict__ A, const unsigned short* __restrict__ Bt,
    void* __restrict__ Dv, const float* __restrict__ bias,
    const float* __restrict__ resid,
    int M, int N, int K, float scale, long sA, long sB, long sD, long sR) {
  __shared__ unsigned short lsA[2][128 * 32];
  __shared__ unsigned short lsB[2][128 * 32];
  const int tid = threadIdx.x;
  const int w = tid >> 6, lane = tid & 63;
  const int wr = w >> 1, wc = w & 1;
  const int b = blockIdx.z;
  const int bm0 = blockIdx.y * 128, bn0 = blockIdx.x * 128;
  const unsigned short* Ab = A + (size_t)b * sA;
  const unsigned short* Bb = Bt + (size_t)b * sB;

  f32x4 acc[4][4] = {};
  const int r0  = w * 16 + (lane >> 2);
  const int kof = (lane & 3) * 8;
  const int fr  = lane & 15, kf = (lane >> 4) * 8;

  for (int it = 0; it < 2; ++it) {
    int row = it * 64 + r0;
    async_copy16(Ab + (size_t)(bm0 + row) * K + kof, &lsA[0][row * 32 + kof]);
    async_copy16(Bb + (size_t)(bn0 + row) * K + kof, &lsB[0][row * 32 + kof]);
  }
  __syncthreads();

  int cur = 0;
  for (int k0 = 0; k0 < K; k0 += 32) {
    const int nk = k0 + 32;
    if (nk < K) {
      for (int it = 0; it < 2; ++it) {
        int row = it * 64 + r0;
        async_copy16(Ab + (size_t)(bm0 + row) * K + nk + kof, &lsA[cur ^ 1][row * 32 + kof]);
        async_copy16(Bb + (size_t)(bn0 + row) * K + nk + kof, &lsB[cur ^ 1][row * 32 + kof]);
      }
    }
    bf16x8 af[4], bff[4];
    for (int i = 0; i < 4; ++i) {
      af[i]  = *(const bf16x8*)(&lsA[cur][(wr * 64 + i * 16 + fr) * 32 + kf]);
      bff[i] = *(const bf16x8*)(&lsB[cur][(wc * 64 + i * 16 + fr) * 32 + kf]);
    }
    for (int i = 0; i < 4; ++i)
      for (int j = 0; j < 4; ++j)
        acc[i][j] = __builtin_amdgcn_mfma_f32_16x16x32_bf16(af[i], bff[j], acc[i][j], 0, 0, 0);
    __syncthreads();
    cur ^= 1;
  }

  const int col_l = lane & 15, row_l = (lane >> 4) * 4;
  for (int i = 0; i < 4; ++i)
    for (int j = 0; j < 4; ++j) {
      int gr = bm0 + wr * 64 + i * 16 + row_l;
      int gc = bn0 + wc * 64 + j * 16 + col_l;
      for (int r = 0; r < 4; ++r) {
        float v = acc[i][j][r] * scale;
        if (BIAS_MODE == 1) v += bias[gr + r];
        if (BIAS_MODE == 2) v += bias[gc];
        if (RESID) v += resid[(size_t)b * sR + (size_t)(gr + r) * N + gc];
        if (OUT_MODE == 1)
          ((unsigned short*)Dv)[(size_t)b * sD + (size_t)(gr + r) * N + gc] = f2bf(v);
        else
          ((float*)Dv)[(size_t)b * sD + (size_t)(gr + r) * N + gc] = v;
      }
    }
}

// ---------------- NT GEMM 256x256, BK=64, 8 waves, m201-style phases ----
// Parts: 0 = A rows bit6==0, 1 = B rows bit5==0, 2 = A rows bit6==1,
//        3 = B rows bit5==1. Phase q of tile t stages part q of tile t+1.
// Phase reads: ph0 {A0(8), B0(4)}, ph1 {A1(8)}, ph2 {B1(4)}, ph3 {}.
// Waits (per-thread loads, 2/part): ph0 vmcnt(2) [publishes p2 for ph1],
// ph1 vmcnt(2) [publishes p3 for ph2], ph3 vmcnt(2) [publishes p0,p1 for
// next ph0]. Tail: ph0 vmcnt(2), ph1 vmcnt(0). Each phase:
// reads -> stage -> s_barrier -> setprio(1) 16 MFMA setprio(0) -> s_barrier.
template <int OUT_MODE, int SPLITK, int EXPL>
__global__ __launch_bounds__(512, 2) void gemm256(
    const unsigned short* __restrict__ A, const unsigned short* __restrict__ Bt,
    void* __restrict__ Dv, float* __restrict__ lsum,
    int M, int N, int K, float scale, long sA, long sB, long sD, int kLen) {
  __shared__ unsigned short lsA[2][256 * 64];
  __shared__ unsigned short lsB[2][256 * 64];
  const int tid = threadIdx.x;
  const int wid = tid >> 6, lane = tid & 63;
  const int wm = wid >> 2, wn = wid & 3;      // 2 x 4 wave grid
  const int fr = lane & 15, kq = lane >> 4;
  const int b = SPLITK ? (blockIdx.z & 3) : blockIdx.z;
  const int bm0 = blockIdx.y * 256, bn0 = blockIdx.x * 256;
  const unsigned short* Ab = A + (size_t)b * sA;
  const unsigned short* Bb = Bt + (size_t)b * sB;
  const size_t dOff = SPLITK ? (size_t)blockIdx.z * (size_t)M * N
                             : (size_t)b * (size_t)sD;
  const int kStart = SPLITK ? (blockIdx.z >> 2) * kLen : 0;
  const int ntiles = (SPLITK ? kLen : K) >> 6;

  const int srow = tid >> 3;                 // 0..63
  const int schunk = (tid & 7) ^ (srow & 7); // pre-swizzled global chunk
  const int s5 = srow >> 5, sl = srow & 31;

  auto stage_part = [&](int t, int buf, int part) {
    const int k0 = kStart + t * 64;
    if (part == 0 || part == 2) {            // A rows with bit6 == part>>1
      const int mh = part >> 1;
#pragma unroll
      for (int i = 0; i < 2; ++i) {
        const int rl = i * 128 + mh * 64 + srow;
        async_copy16(Ab + (size_t)(bm0 + rl) * K + k0 + schunk * 8,
                     &lsA[buf][rl * 64 + (tid & 7) * 8]);
      }
    } else {                                 // B rows with bit5 == part>>1
      const int nh = part >> 1;
#pragma unroll
      for (int i = 0; i < 2; ++i) {
        const int rl = i * 128 + s5 * 64 + nh * 32 + sl;
        async_copy16(Bb + (size_t)(bn0 + rl) * K + k0 + schunk * 8,
                     &lsB[buf][rl * 64 + (tid & 7) * 8]);
      }
    }
  };

  f32x4 acc[8][4] = {};
  const int cko0 = (((0 * 4 + kq) ^ (fr & 7)) * 8);
  const int cko1 = (((1 * 4 + kq) ^ (fr & 7)) * 8);
  const int arow = wm * 128 + fr;
  const int brow = wn * 64 + fr;

#define MMA8(AF, BG, MO, NO)                                                  \
  __builtin_amdgcn_s_setprio(1);                                              \
  _Pragma("unroll")                                                           \
  for (int i = 0; i < 4; ++i)                                                 \
    _Pragma("unroll")                                                         \
    for (int j = 0; j < 2; ++j) {                                             \
      acc[(MO) + i][(NO) + j] = __builtin_amdgcn_mfma_f32_16x16x32_bf16(      \
          AF[i][0], BG[j][0], acc[(MO) + i][(NO) + j], 0, 0, 0);              \
      acc[(MO) + i][(NO) + j] = __builtin_amdgcn_mfma_f32_16x16x32_bf16(      \
          AF[i][1], BG[j][1], acc[(MO) + i][(NO) + j], 0, 0, 0);              \
    }                                                                         \
  __builtin_amdgcn_s_setprio(0);

  // prologue: all 4 parts of tile 0; publish p0,p1 (retire first 4 loads)
  stage_part(0, 0, 0); stage_part(0, 0, 1);
  stage_part(0, 0, 2); stage_part(0, 0, 3);
  asm volatile("s_waitcnt vmcnt(4)\n\ts_barrier" ::: "memory");

  for (int t = 0; t < ntiles; ++t) {
    const int cur = t & 1, nbuf = cur ^ 1;
    const unsigned short* la = &lsA[cur][0];
    const unsigned short* lb = &lsB[cur][0];
    const bool pre = (t + 1 < ntiles);
    bf16x8 af0[4][2], af1[4][2], bg0[2][2], bg1[2][2];

    // ---- phase 0: (mh0,nh0); wait publishes p2 for ph1 ----
    asm volatile("s_waitcnt vmcnt(2)" ::: "memory");
#pragma unroll
    for (int i = 0; i < 4; ++i) {
      const int ra = (arow + i * 16) * 64;
      af0[i][0] = *(const bf16x8*)&la[ra + cko0];
      af0[i][1] = *(const bf16x8*)&la[ra + cko1];
    }
#pragma unroll
    for (int j = 0; j < 2; ++j) {
      const int rb = (brow + j * 16) * 64;
      bg0[j][0] = *(const bf16x8*)&lb[rb + cko0];
      bg0[j][1] = *(const bf16x8*)&lb[rb + cko1];
    }
    if (pre) stage_part(t + 1, nbuf, 0);
    asm volatile("s_barrier" ::: "memory");
    MMA8(af0, bg0, 0, 0)
    asm volatile("s_barrier" ::: "memory");

    // ---- phase 1: (mh1,nh0); wait publishes p3 for ph2 ----
    if (pre) asm volatile("s_waitcnt vmcnt(2)" ::: "memory");
    else     asm volatile("s_waitcnt vmcnt(0)" ::: "memory");
#pragma unroll
    for (int i = 0; i < 4; ++i) {
      const int ra = (arow + 64 + i * 16) * 64;
      af1[i][0] = *(const bf16x8*)&la[ra + cko0];
      af1[i][1] = *(const bf16x8*)&la[ra + cko1];
    }
    if (pre) stage_part(t + 1, nbuf, 1);
    asm volatile("s_barrier" ::: "memory");
    MMA8(af1, bg0, 4, 0)
    asm volatile("s_barrier" ::: "memory");

    // ---- phase 2: (mh1,nh1); no wait needed ----
#pragma unroll
    for (int j = 0; j < 2; ++j) {
      const int rb = (brow + 32 + j * 16) * 64;
      bg1[j][0] = *(const bf16x8*)&lb[rb + cko0];
      bg1[j][1] = *(const bf16x8*)&lb[rb + cko1];
    }
    if (pre) stage_part(t + 1, nbuf, 2);
    asm volatile("s_barrier" ::: "memory");
    MMA8(af1, bg1, 4, 2)
    asm volatile("s_barrier" ::: "memory");

    // ---- phase 3: (mh0,nh1); wait publishes next p0,p1 ----
    if (pre) {
      asm volatile("s_waitcnt vmcnt(2)" ::: "memory");
      stage_part(t + 1, nbuf, 3);
    }
    asm volatile("s_barrier" ::: "memory");
    MMA8(af0, bg1, 0, 2)
    asm volatile("s_barrier" ::: "memory");
  }
#undef MMA8

  // epilogue
  float rs[8][4];
  if (EXPL)
#pragma unroll
    for (int i = 0; i < 8; ++i)
#pragma unroll
      for (int r = 0; r < 4; ++r) rs[i][r] = 0.f;

#pragma unroll
  for (int mi = 0; mi < 8; ++mi)
#pragma unroll
    for (int ni = 0; ni < 4; ++ni) {
      const int gr = bm0 + wm * 128 + mi * 16 + kq * 4;
      const int gc = bn0 + wn * 64 + ni * 16 + fr;
#pragma unroll
      for (int r = 0; r < 4; ++r) {
        float v;
        if (EXPL) {
          v = __expf(fmaf(acc[mi][ni][r], scale, -M0));
          rs[mi][r] += v;
        } else {
          v = acc[mi][ni][r] * scale;
        }
        if (OUT_MODE == 1)
          ((unsigned short*)Dv)[dOff + (size_t)(gr + r) * N + gc] = f2bf(v);
        else
          ((_Float16*)Dv)[dOff + (size_t)(gr + r) * N + gc] = (_Float16)v;
      }
    }

  if (EXPL) {
#pragma unroll
    for (int mi = 0; mi < 8; ++mi)
#pragma unroll
      for (int r = 0; r < 4; ++r) {
        float v = rs[mi][r];
        v += __shfl_xor(v, 1); v += __shfl_xor(v, 2);
        v += __shfl_xor(v, 4); v += __shfl_xor(v, 8);
        if (fr == 0) {
          int gr = bm0 + wm * 128 + mi * 16 + kq * 4 + r;
          atomicAdd(&lsum[(size_t)b * M + gr], v);
        }
      }
  }
}

// ---------------- reduce: ot = (Op0 + Op1) / l  -> bf16 ----------------
__global__ __launch_bounds__(256) void reduce_div(const _Float16* __restrict__ Op,
                                                  const float* __restrict__ l,
                                                  unsigned short* __restrict__ ot) {
  const size_t stride = (size_t)NB * NSP * CDIM;  // elems per split
  size_t base = ((size_t)blockIdx.x * 256 + threadIdx.x) * 8;
  float linv = 1.f / l[base >> 9];  // row = base / 512
  h8 a = *(const h8*)(Op + base);
  h8 c = *(const h8*)(Op + stride + base);
  u16x4 o0, o1;
#pragma unroll
  for (int i = 0; i < 4; ++i) {
    o0[i] = f2bf(((float)a[i] + (float)c[i]) * linv);
    o1[i] = f2bf(((float)a[i + 4] + (float)c[i + 4]) * linv);
  }
  *(u16x4*)(ot + base) = o0;
  *(u16x4*)(ot + base + 4) = o1;
}

extern "C" void kernel_launch(void* const* d_in, const int* in_sizes, int n_in,
                              void* d_out, int out_size, void* d_ws, size_t ws_size,
                              hipStream_t stream) {
  const float* hs  = (const float*)d_in[0];
  const float* gns = (const float*)d_in[1];
  const float* gnb = (const float*)d_in[2];
  const float* wq  = (const float*)d_in[3];
  const float* bq  = (const float*)d_in[4];
  const float* wk  = (const float*)d_in[5];
  const float* bk  = (const float*)d_in[6];
  const float* wv  = (const float*)d_in[7];
  const float* bv  = (const float*)d_in[8];
  const float* wp  = (const float*)d_in[9];
  const float* bp  = (const float*)d_in[10];

  char* p = (char*)d_ws;
  unsigned short* wqb = (unsigned short*)p; p += (size_t)CDIM * CDIM * 2;
  unsigned short* wkb = (unsigned short*)p; p += (size_t)CDIM * CDIM * 2;
  unsigned short* wvb = (unsigned short*)p; p += (size_t)CDIM * CDIM * 2;
  unsigned short* wpb = (unsigned short*)p; p += (size_t)CDIM * CDIM * 2;
  const size_t bn = (size_t)NSP * CDIM;  // 2M elements per batch
  unsigned short* hnt = (unsigned short*)p; p += NB * bn * 2;   // also reused as ot
  unsigned short* qt  = (unsigned short*)p; p += NB * bn * 2;
  unsigned short* kt  = (unsigned short*)p; p += NB * bn * 2;
  unsigned short* vcn = (unsigned short*)p; p += NB * bn * 2;
  unsigned short* P   = (unsigned short*)p; p += (size_t)NB * NSP * NSP * 2;  // 128 MiB
  _Float16* Op = (_Float16*)p;  p += (size_t)2 * NB * bn * 2;   // 32 MiB (2 splits)
  float* lsum  = (float*)p;     p += (size_t)NB * NSP * 4;      // 64 KiB
  float* stats = (float*)p;     p += 256 * 4;
  unsigned short* ot = hnt;  // hnt dead after the QKV projections

  hipMemsetAsync(lsum, 0, (size_t)NB * NSP * 4, stream);
  weights_to_bf16<<<dim3(256, 4), 256, 0, stream>>>(wq, wk, wv, wp, wqb, wkb, wvb, wpb);
  gn_stats<<<128, 256, 0, stream>>>(hs, stats);
  norm_transpose<<<dim3(64, 8, 4), 256, 0, stream>>>(hs, stats, gns, gnb, hnt);

  const long sBN = (long)bn;
  const long sPP = (long)NSP * NSP;
  // Qt[b] (4096x512) = Hnt[b] @ Wq^T + bq (per-col)
  gemm_nt<2, 1, 0><<<dim3(4, 32, NB), 256, 0, stream>>>(
      hnt, wqb, qt, bq, nullptr, NSP, CDIM, CDIM, 1.f, sBN, 0, sBN, 0);
  gemm_nt<2, 1, 0><<<dim3(4, 32, NB), 256, 0, stream>>>(
      hnt, wkb, kt, bk, nullptr, NSP, CDIM, CDIM, 1.f, sBN, 0, sBN, 0);
  // Vcn[b] (512x4096) = Wv @ Hnt[b]^T + bv (per-row)
  gemm_nt<1, 1, 0><<<dim3(32, 4, NB), 256, 0, stream>>>(
      wvb, hnt, vcn, bv, nullptr, CDIM, NSP, CDIM, 1.f, 0, sBN, sBN, 0);

  // P[b] (4096x4096 bf16) = exp(Qt Kt^T * C^-0.5 - M0); lsum[b][i] += row sums
  const float sc = 0.044194173824159216f;  // 512^-0.5
  gemm256<1, 0, 1><<<dim3(16, 16, NB), 512, 0, stream>>>(
      qt, kt, P, lsum, NSP, NSP, CDIM, sc, sBN, sBN, sPP, 0);

  // PV split-K=2: Op[z] (4096x512 fp16) = P[b][:, ks:+2048] @ Vcn[b][:, same]^T
  gemm256<2, 1, 0><<<dim3(2, 16, 2 * NB), 512, 0, stream>>>(
      P, vcn, Op, nullptr, NSP, CDIM, NSP, 1.f, sPP, sBN, 0, NSP / 2);

  // ot (bf16) = (Op0 + Op1) / lsum
  reduce_div<<<4096, 256, 0, stream>>>(Op, lsum, ot);

  // out[b] (512x4096 fp32) = Wp @ Ot[b]^T + bp (per-row) + residual
  gemm_nt<1, 0, 1><<<dim3(32, 4, NB), 256, 0, stream>>>(
      wpb, ot, (float*)d_out, bp, hs, CDIM, NSP, CDIM, 1.f, 0, sBN, sBN, sBN);
}

// Round 10
// 317.420 us; speedup vs baseline: 1.3017x; 1.0029x over previous
//
#include <hip/hip_runtime.h>
#include <cstdint>
#include <cstddef>

// AttnBlock: B=4, C=512, H=W=64 (N=4096). All-fp32 I/O, bf16 MFMA internally.
// R10: R9 + rule-#18 fences: each phase's MFMA cluster pinned between
//      barriers via asm lgkmcnt(0) + sched_barrier(0) (hipcc hoists
//      register-only MFMA past asm barriers otherwise). vmcnt waits moved
//      after the stage issue, counts {4,4,-,4}, tail {2,0,-,-}.

#define CDIM 512
#define NSP  4096
#define NB   4
#define M0   12.0f

using bf16x8 = __attribute__((ext_vector_type(8))) __bf16;
using f32x4  = __attribute__((ext_vector_type(4))) float;
using u16x4  = __attribute__((ext_vector_type(4))) unsigned short;
using h8     = __attribute__((ext_vector_type(8))) _Float16;

__device__ __forceinline__ unsigned short f2bf(float f) {
  unsigned int u = __float_as_uint(f);
  u += 0x7fffu + ((u >> 16) & 1u);
  return (unsigned short)(u >> 16);
}

__device__ __forceinline__ void async_copy16(const unsigned short* g, unsigned short* l) {
  __builtin_amdgcn_global_load_lds(
      (const __attribute__((address_space(1))) void*)g,
      (__attribute__((address_space(3))) void*)l, 16, 0, 0);
}

// ---------------- GroupNorm stats: one block per (b, group) ----------------
__global__ __launch_bounds__(256) void gn_stats(const float* __restrict__ x,
                                                float* __restrict__ stats) {
  const size_t base = (size_t)blockIdx.x * 65536;  // 16 ch * 4096, contiguous
  const float4* p = (const float4*)(x + base);
  float s = 0.f, ss = 0.f;
  for (int i = threadIdx.x; i < 16384; i += 256) {
    float4 v = p[i];
    s  += v.x + v.y + v.z + v.w;
    ss += v.x*v.x + v.y*v.y + v.z*v.z + v.w*v.w;
  }
  for (int off = 32; off; off >>= 1) {
    s  += __shfl_xor(s, off);
    ss += __shfl_xor(ss, off);
  }
  __shared__ float rs[4], rss[4];
  const int w = threadIdx.x >> 6;
  if ((threadIdx.x & 63) == 0) { rs[w] = s; rss[w] = ss; }
  __syncthreads();
  if (threadIdx.x == 0) {
    float S  = rs[0] + rs[1] + rs[2] + rs[3];
    float SS = rss[0] + rss[1] + rss[2] + rss[3];
    float mean = S * (1.f / 65536.f);
    float var  = SS * (1.f / 65536.f) - mean * mean;
    stats[2 * blockIdx.x]     = mean;
    stats[2 * blockIdx.x + 1] = rsqrtf(var + 1e-6f);
  }
}

// ------------- normalize + transpose: x(B,C,N) f32 -> Hnt(B,N,C) bf16 -------
__global__ __launch_bounds__(256) void norm_transpose(
    const float* __restrict__ x, const float* __restrict__ stats,
    const float* __restrict__ gns, const float* __restrict__ gnb,
    unsigned short* __restrict__ hnt) {
  __shared__ float tile[64][65];
  const int b  = blockIdx.z;
  const int c0 = blockIdx.y * 64, n0 = blockIdx.x * 64;
  const int tx = threadIdx.x & 63, ty = threadIdx.x >> 6;
  for (int i = 0; i < 16; ++i) {
    int cl = ty * 16 + i;
    int c  = c0 + cl;
    int g  = c >> 4;
    float mean = stats[(b * 32 + g) * 2];
    float rstd = stats[(b * 32 + g) * 2 + 1];
    float v = x[((size_t)(b * CDIM + c)) * NSP + n0 + tx];
    tile[cl][tx] = (v - mean) * rstd * gns[c] + gnb[c];
  }
  __syncthreads();
  for (int i = 0; i < 16; ++i) {
    int nl = ty * 16 + i;
    hnt[((size_t)(b * NSP + n0 + nl)) * CDIM + c0 + tx] = f2bf(tile[tx][nl]);
  }
}

// ---------------- fp32 -> bf16 weight conversion (4 weights, one launch) ----
__global__ __launch_bounds__(256) void weights_to_bf16(
    const float* __restrict__ w0, const float* __restrict__ w1,
    const float* __restrict__ w2, const float* __restrict__ w3,
    unsigned short* __restrict__ o0, unsigned short* __restrict__ o1,
    unsigned short* __restrict__ o2, unsigned short* __restrict__ o3) {
  const float* s; unsigned short* o;
  switch (blockIdx.y) {
    case 0: s = w0; o = o0; break;
    case 1: s = w1; o = o1; break;
    case 2: s = w2; o = o2; break;
    default: s = w3; o = o3; break;
  }
  int i = blockIdx.x * 256 + threadIdx.x;
  float4 v = ((const float4*)s)[i];
  u16x4 r = {f2bf(v.x), f2bf(v.y), f2bf(v.z), f2bf(v.w)};
  *(u16x4*)(o + (size_t)i * 4) = r;
}

// ---------------- NT GEMM 128x128 (R4-proven, for the small projections) ----
template <int BIAS_MODE, int OUT_MODE, int RESID>
__global__ __launch_bounds__(256) void gemm_nt(
    const unsigned short* __restrict__ A, const unsigned short* __restrict__ Bt,
    void* __restrict__ Dv, const float* __restrict__ bias,
    const float* __restrict__ resid,
    int M, int N, int K, float scale, long sA, long sB, long sD, long sR) {
  __shared__ unsigned short lsA[2][128 * 32];
  __shared__ unsigned short lsB[2][128 * 32];
  const int tid = threadIdx.x;
  const int w = tid >> 6, lane = tid & 63;
  const int wr = w >> 1, wc = w & 1;
  const int b = blockIdx.z;
  const int bm0 = blockIdx.y * 128, bn0 = blockIdx.x * 128;
  const unsigned short* Ab = A + (size_t)b * sA;
  const unsigned short* Bb = Bt + (size_t)b * sB;

  f32x4 acc[4][4] = {};
  const int r0  = w * 16 + (lane >> 2);
  const int kof = (lane & 3) * 8;
  const int fr  = lane & 15, kf = (lane >> 4) * 8;

  for (int it = 0; it < 2; ++it) {
    int row = it * 64 + r0;
    async_copy16(Ab + (size_t)(bm0 + row) * K + kof, &lsA[0][row * 32 + kof]);
    async_copy16(Bb + (size_t)(bn0 + row) * K + kof, &lsB[0][row * 32 + kof]);
  }
  __syncthreads();

  int cur = 0;
  for (int k0 = 0; k0 < K; k0 += 32) {
    const int nk = k0 + 32;
    if (nk < K) {
      for (int it = 0; it < 2; ++it) {
        int row = it * 64 + r0;
        async_copy16(Ab + (size_t)(bm0 + row) * K + nk + kof, &lsA[cur ^ 1][row * 32 + kof]);
        async_copy16(Bb + (size_t)(bn0 + row) * K + nk + kof, &lsB[cur ^ 1][row * 32 + kof]);
      }
    }
    bf16x8 af[4], bff[4];
    for (int i = 0; i < 4; ++i) {
      af[i]  = *(const bf16x8*)(&lsA[cur][(wr * 64 + i * 16 + fr) * 32 + kf]);
      bff[i] = *(const bf16x8*)(&lsB[cur][(wc * 64 + i * 16 + fr) * 32 + kf]);
    }
    for (int i = 0; i < 4; ++i)
      for (int j = 0; j < 4; ++j)
        acc[i][j] = __builtin_amdgcn_mfma_f32_16x16x32_bf16(af[i], bff[j], acc[i][j], 0, 0, 0);
    __syncthreads();
    cur ^= 1;
  }

  const int col_l = lane & 15, row_l = (lane >> 4) * 4;
  for (int i = 0; i < 4; ++i)
    for (int j = 0; j < 4; ++j) {
      int gr = bm0 + wr * 64 + i * 16 + row_l;
      int gc = bn0 + wc * 64 + j * 16 + col_l;
      for (int r = 0; r < 4; ++r) {
        float v = acc[i][j][r] * scale;
        if (BIAS_MODE == 1) v += bias[gr + r];
        if (BIAS_MODE == 2) v += bias[gc];
        if (RESID) v += resid[(size_t)b * sR + (size_t)(gr + r) * N + gc];
        if (OUT_MODE == 1)
          ((unsigned short*)Dv)[(size_t)b * sD + (size_t)(gr + r) * N + gc] = f2bf(v);
        else
          ((float*)Dv)[(size_t)b * sD + (size_t)(gr + r) * N + gc] = v;
      }
    }
}

// ---------------- NT GEMM 256x256, BK=64, 8 waves, fenced phase schedule ----
// As R9, plus: MFMA clusters pinned between barriers (asm lgkmcnt(0) +
// sched_barrier(0) fences, rule #18); vmcnt waits after stage issue with
// counts {4,4,-,4} steady / {2,0,-,-} tail (FIFO ledger verified).
template <int OUT_MODE, int SPLITK, int EXPL>
__global__ __launch_bounds__(512, 2) void gemm256(
    const unsigned short* __restrict__ A, const unsigned short* __restrict__ Bt,
    void* __restrict__ Dv, float* __restrict__ lsum,
    int M, int N, int K, float scale, long sA, long sB, long sD, int kLen) {
  __shared__ unsigned short lsA[2][256 * 64];
  __shared__ unsigned short lsB[2][256 * 64];
  const int tid = threadIdx.x;
  const int wid = tid >> 6, lane = tid & 63;
  const int wm = wid >> 2, wn = wid & 3;      // 2 x 4 wave grid
  const int fr = lane & 15, kq = lane >> 4;
  const int b = SPLITK ? (blockIdx.z & 3) : blockIdx.z;
  const int bm0 = blockIdx.y * 256, bn0 = blockIdx.x * 256;
  const unsigned short* Ab = A + (size_t)b * sA;
  const unsigned short* Bb = Bt + (size_t)b * sB;
  const size_t dOff = SPLITK ? (size_t)blockIdx.z * (size_t)M * N
                             : (size_t)b * (size_t)sD;
  const int kStart = SPLITK ? (blockIdx.z >> 2) * kLen : 0;
  const int ntiles = (SPLITK ? kLen : K) >> 6;

  const int srow = tid >> 3;                 // 0..63
  const int schunk = (tid & 7) ^ (srow & 7); // pre-swizzled global chunk
  const int s5 = srow >> 5, sl = srow & 31;

  auto stage_part = [&](int t, int buf, int part) {
    const int k0 = kStart + t * 64;
    if (part == 0 || part == 2) {            // A rows with bit6 == part>>1
      const int mh = part >> 1;
#pragma unroll
      for (int i = 0; i < 2; ++i) {
        const int rl = i * 128 + mh * 64 + srow;
        async_copy16(Ab + (size_t)(bm0 + rl) * K + k0 + schunk * 8,
                     &lsA[buf][rl * 64 + (tid & 7) * 8]);
      }
    } else {                                 // B rows with bit5 == part>>1
      const int nh = part >> 1;
#pragma unroll
      for (int i = 0; i < 2; ++i) {
        const int rl = i * 128 + s5 * 64 + nh * 32 + sl;
        async_copy16(Bb + (size_t)(bn0 + rl) * K + k0 + schunk * 8,
                     &lsB[buf][rl * 64 + (tid & 7) * 8]);
      }
    }
  };

  f32x4 acc[8][4] = {};
  const int cko0 = (((0 * 4 + kq) ^ (fr & 7)) * 8);
  const int cko1 = (((1 * 4 + kq) ^ (fr & 7)) * 8);
  const int arow = wm * 128 + fr;
  const int brow = wn * 64 + fr;

// MFMA cluster pinned between the surrounding barriers (rule #18):
// lgkmcnt(0) waits for this phase's ds_reads; sched_barrier(0) stops hipcc
// from hoisting the register-only MFMAs above it / sinking them below.
#define MMA8(AF, BG, MO, NO)                                                  \
  asm volatile("s_waitcnt lgkmcnt(0)" ::: "memory");                          \
  __builtin_amdgcn_sched_barrier(0);                                          \
  __builtin_amdgcn_s_setprio(1);                                              \
  _Pragma("unroll")                                                           \
  for (int i = 0; i < 4; ++i)                                                 \
    _Pragma("unroll")                                                         \
    for (int j = 0; j < 2; ++j) {                                             \
      acc[(MO) + i][(NO) + j] = __builtin_amdgcn_mfma_f32_16x16x32_bf16(      \
          AF[i][0], BG[j][0], acc[(MO) + i][(NO) + j], 0, 0, 0);              \
      acc[(MO) + i][(NO) + j] = __builtin_amdgcn_mfma_f32_16x16x32_bf16(      \
          AF[i][1], BG[j][1], acc[(MO) + i][(NO) + j], 0, 0, 0);              \
    }                                                                         \
  __builtin_amdgcn_s_setprio(0);                                              \
  __builtin_amdgcn_sched_barrier(0);

  // prologue: all 4 parts of tile 0; publish p0,p1 (retire first 4 loads)
  stage_part(0, 0, 0); stage_part(0, 0, 1);
  stage_part(0, 0, 2); stage_part(0, 0, 3);
  asm volatile("s_waitcnt vmcnt(4)\n\ts_barrier" ::: "memory");

  for (int t = 0; t < ntiles; ++t) {
    const int cur = t & 1, nbuf = cur ^ 1;
    const unsigned short* la = &lsA[cur][0];
    const unsigned short* lb = &lsB[cur][0];
    const bool pre = (t + 1 < ntiles);
    bf16x8 af0[4][2], af1[4][2], bg0[2][2], bg1[2][2];

    // ---- phase 0: (mh0,nh0); wait publishes p2(t) for ph1 ----
#pragma unroll
    for (int i = 0; i < 4; ++i) {
      const int ra = (arow + i * 16) * 64;
      af0[i][0] = *(const bf16x8*)&la[ra + cko0];
      af0[i][1] = *(const bf16x8*)&la[ra + cko1];
    }
#pragma unroll
    for (int j = 0; j < 2; ++j) {
      const int rb = (brow + j * 16) * 64;
      bg0[j][0] = *(const bf16x8*)&lb[rb + cko0];
      bg0[j][1] = *(const bf16x8*)&lb[rb + cko1];
    }
    if (pre) {
      stage_part(t + 1, nbuf, 0);
      asm volatile("s_waitcnt vmcnt(4)" ::: "memory");
    } else {
      asm volatile("s_waitcnt vmcnt(2)" ::: "memory");
    }
    asm volatile("s_barrier" ::: "memory");
    MMA8(af0, bg0, 0, 0)
    asm volatile("s_barrier" ::: "memory");

    // ---- phase 1: (mh1,nh0); wait publishes p3(t) for ph2 ----
#pragma unroll
    for (int i = 0; i < 4; ++i) {
      const int ra = (arow + 64 + i * 16) * 64;
      af1[i][0] = *(const bf16x8*)&la[ra + cko0];
      af1[i][1] = *(const bf16x8*)&la[ra + cko1];
    }
    if (pre) {
      stage_part(t + 1, nbuf, 1);
      asm volatile("s_waitcnt vmcnt(4)" ::: "memory");
    } else {
      asm volatile("s_waitcnt vmcnt(0)" ::: "memory");
    }
    asm volatile("s_barrier" ::: "memory");
    MMA8(af1, bg0, 4, 0)
    asm volatile("s_barrier" ::: "memory");

    // ---- phase 2: (mh1,nh1); no wait needed ----
#pragma unroll
    for (int j = 0; j < 2; ++j) {
      const int rb = (brow + 32 + j * 16) * 64;
      bg1[j][0] = *(const bf16x8*)&lb[rb + cko0];
      bg1[j][1] = *(const bf16x8*)&lb[rb + cko1];
    }
    if (pre) stage_part(t + 1, nbuf, 2);
    asm volatile("s_barrier" ::: "memory");
    MMA8(af1, bg1, 4, 2)
    asm volatile("s_barrier" ::: "memory");

    // ---- phase 3: (mh0,nh1); wait publishes p0,p1(t+1) for next ph0 ----
    if (pre) {
      stage_part(t + 1, nbuf, 3);
      asm volatile("s_waitcnt vmcnt(4)" ::: "memory");
    }
    asm volatile("s_barrier" ::: "memory");
    MMA8(af0, bg1, 0, 2)
    asm volatile("s_barrier" ::: "memory");
  }
#undef MMA8

  // epilogue
  float rs[8][4];
  if (EXPL)
#pragma unroll
    for (int i = 0; i < 8; ++i)
#pragma unroll
      for (int r = 0; r < 4; ++r) rs[i][r] = 0.f;

#pragma unroll
  for (int mi = 0; mi < 8; ++mi)
#pragma unroll
    for (int ni = 0; ni < 4; ++ni) {
      const int gr = bm0 + wm * 128 + mi * 16 + kq * 4;
      const int gc = bn0 + wn * 64 + ni * 16 + fr;
#pragma unroll
      for (int r = 0; r < 4; ++r) {
        float v;
        if (EXPL) {
          v = __expf(fmaf(acc[mi][ni][r], scale, -M0));
          rs[mi][r] += v;
        } else {
          v = acc[mi][ni][r] * scale;
        }
        if (OUT_MODE == 1)
          ((unsigned short*)Dv)[dOff + (size_t)(gr + r) * N + gc] = f2bf(v);
        else
          ((_Float16*)Dv)[dOff + (size_t)(gr + r) * N + gc] = (_Float16)v;
      }
    }

  if (EXPL) {
#pragma unroll
    for (int mi = 0; mi < 8; ++mi)
#pragma unroll
      for (int r = 0; r < 4; ++r) {
        float v = rs[mi][r];
        v += __shfl_xor(v, 1); v += __shfl_xor(v, 2);
        v += __shfl_xor(v, 4); v += __shfl_xor(v, 8);
        if (fr == 0) {
          int gr = bm0 + wm * 128 + mi * 16 + kq * 4 + r;
          atomicAdd(&lsum[(size_t)b * M + gr], v);
        }
      }
  }
}

// ---------------- reduce: ot = (Op0 + Op1) / l  -> bf16 ----------------
__global__ __launch_bounds__(256) void reduce_div(const _Float16* __restrict__ Op,
                                                  const float* __restrict__ l,
                                                  unsigned short* __restrict__ ot) {
  const size_t stride = (size_t)NB * NSP * CDIM;  // elems per split
  size_t base = ((size_t)blockIdx.x * 256 + threadIdx.x) * 8;
  float linv = 1.f / l[base >> 9];  // row = base / 512
  h8 a = *(const h8*)(Op + base);
  h8 c = *(const h8*)(Op + stride + base);
  u16x4 o0, o1;
#pragma unroll
  for (int i = 0; i < 4; ++i) {
    o0[i] = f2bf(((float)a[i] + (float)c[i]) * linv);
    o1[i] = f2bf(((float)a[i + 4] + (float)c[i + 4]) * linv);
  }
  *(u16x4*)(ot + base) = o0;
  *(u16x4*)(ot + base + 4) = o1;
}

extern "C" void kernel_launch(void* const* d_in, const int* in_sizes, int n_in,
                              void* d_out, int out_size, void* d_ws, size_t ws_size,
                              hipStream_t stream) {
  const float* hs  = (const float*)d_in[0];
  const float* gns = (const float*)d_in[1];
  const float* gnb = (const float*)d_in[2];
  const float* wq  = (const float*)d_in[3];
  const float* bq  = (const float*)d_in[4];
  const float* wk  = (const float*)d_in[5];
  const float* bk  = (const float*)d_in[6];
  const float* wv  = (const float*)d_in[7];
  const float* bv  = (const float*)d_in[8];
  const float* wp  = (const float*)d_in[9];
  const float* bp  = (const float*)d_in[10];

  char* p = (char*)d_ws;
  unsigned short* wqb = (unsigned short*)p; p += (size_t)CDIM * CDIM * 2;
  unsigned short* wkb = (unsigned short*)p; p += (size_t)CDIM * CDIM * 2;
  unsigned short* wvb = (unsigned short*)p; p += (size_t)CDIM * CDIM * 2;
  unsigned short* wpb = (unsigned short*)p; p += (size_t)CDIM * CDIM * 2;
  const size_t bn = (size_t)NSP * CDIM;  // 2M elements per batch
  unsigned short* hnt = (unsigned short*)p; p += NB * bn * 2;   // also reused as ot
  unsigned short* qt  = (unsigned short*)p; p += NB * bn * 2;
  unsigned short* kt  = (unsigned short*)p; p += NB * bn * 2;
  unsigned short* vcn = (unsigned short*)p; p += NB * bn * 2;
  unsigned short* P   = (unsigned short*)p; p += (size_t)NB * NSP * NSP * 2;  // 128 MiB
  _Float16* Op = (_Float16*)p;  p += (size_t)2 * NB * bn * 2;   // 32 MiB (2 splits)
  float* lsum  = (float*)p;     p += (size_t)NB * NSP * 4;      // 64 KiB
  float* stats = (float*)p;     p += 256 * 4;
  unsigned short* ot = hnt;  // hnt dead after the QKV projections

  hipMemsetAsync(lsum, 0, (size_t)NB * NSP * 4, stream);
  weights_to_bf16<<<dim3(256, 4), 256, 0, stream>>>(wq, wk, wv, wp, wqb, wkb, wvb, wpb);
  gn_stats<<<128, 256, 0, stream>>>(hs, stats);
  norm_transpose<<<dim3(64, 8, 4), 256, 0, stream>>>(hs, stats, gns, gnb, hnt);

  const long sBN = (long)bn;
  const long sPP = (long)NSP * NSP;
  // Qt[b] (4096x512) = Hnt[b] @ Wq^T + bq (per-col)
  gemm_nt<2, 1, 0><<<dim3(4, 32, NB), 256, 0, stream>>>(
      hnt, wqb, qt, bq, nullptr, NSP, CDIM, CDIM, 1.f, sBN, 0, sBN, 0);
  gemm_nt<2, 1, 0><<<dim3(4, 32, NB), 256, 0, stream>>>(
      hnt, wkb, kt, bk, nullptr, NSP, CDIM, CDIM, 1.f, sBN, 0, sBN, 0);
  // Vcn[b] (512x4096) = Wv @ Hnt[b]^T + bv (per-row)
  gemm_nt<1, 1, 0><<<dim3(32, 4, NB), 256, 0, stream>>>(
      wvb, hnt, vcn, bv, nullptr, CDIM, NSP, CDIM, 1.f, 0, sBN, sBN, 0);

  // P[b] (4096x4096 bf16) = exp(Qt Kt^T * C^-0.5 - M0); lsum[b][i] += row sums
  const float sc = 0.044194173824159216f;  // 512^-0.5
  gemm256<1, 0, 1><<<dim3(16, 16, NB), 512, 0, stream>>>(
      qt, kt, P, lsum, NSP, NSP, CDIM, sc, sBN, sBN, sPP, 0);

  // PV split-K=2: Op[z] (4096x512 fp16) = P[b][:, ks:+2048] @ Vcn[b][:, same]^T
  gemm256<2, 1, 0><<<dim3(2, 16, 2 * NB), 512, 0, stream>>>(
      P, vcn, Op, nullptr, NSP, CDIM, NSP, 1.f, sPP, sBN, 0, NSP / 2);

  // ot (bf16) = (Op0 + Op1) / lsum
  reduce_div<<<4096, 256, 0, stream>>>(Op, lsum, ot);

  // out[b] (512x4096 fp32) = Wp @ Ot[b]^T + bp (per-row) + residual
  gemm_nt<1, 0, 1><<<dim3(32, 4, NB), 256, 0, stream>>>(
      wpb, ot, (float*)d_out, bp, hs, CDIM, NSP, CDIM, 1.f, 0, sBN, sBN, sBN);
}